// Round 1
// baseline (948.168 us; speedup 1.0000x reference)
//
#include <hip/hip_runtime.h>
#include <hip/hip_bf16.h>
#include <cstddef>

#define N_NODES 40000
#define N_EDGES 8000
#define DE 32
#define DV 8
#define DIM 256
#define QDIM 256
#define EIGD 64
#define NCLS 40
#define LN_EPS 1e-5f
#define ATT_SCALE 0.0625f   // 1/sqrt(256)

__device__ inline float wave_sum(float v) {
#pragma unroll
    for (int off = 32; off > 0; off >>= 1) v += __shfl_down(v, off, 64);
    return v;  // valid in lane 0
}

// ---------------------------------------------------------------------------
// Generic tiled f32 GEMM: C[M,Nd] = act(A[M,K] @ W[K,Nd] + bias (+ resid))
// 64x64 tile, 256 threads, 4x4 micro-tile per thread, BK=16.
// ---------------------------------------------------------------------------
template <int ACT, bool RES>
__global__ __launch_bounds__(256) void gemm_f32(
    const float* __restrict__ A, const float* __restrict__ W,
    const float* __restrict__ bias, const float* __restrict__ resid,
    float* __restrict__ C, int M, int K, int Nd)
{
    __shared__ float As[16][68];  // [k][m], pad 68 (16B-aligned rows, conflict-free)
    __shared__ float Ws[16][68];  // [k][n]
    const int t = threadIdx.x;
    const int tx = t & 15, ty = t >> 4;
    const int row0 = blockIdx.y * 64;
    const int col0 = blockIdx.x * 64;
    float acc[4][4] = {};

    const int am = t >> 2;        // 0..63  (A row within tile)
    const int ak = (t & 3) * 4;   // 0,4,8,12
    const int wk = t >> 4;        // 0..15  (W k within tile)
    const int wn = (t & 15) * 4;  // 0..60

    for (int k0 = 0; k0 < K; k0 += 16) {
        {
            int gr = row0 + am;
            float4 av = make_float4(0.f, 0.f, 0.f, 0.f);
            if (gr < M) av = *(const float4*)&A[(size_t)gr * K + k0 + ak];
            As[ak + 0][am] = av.x; As[ak + 1][am] = av.y;
            As[ak + 2][am] = av.z; As[ak + 3][am] = av.w;
        }
        {
            int gc = col0 + wn;
            const float* wr = &W[(size_t)(k0 + wk) * Nd];
            float4 wv = make_float4(0.f, 0.f, 0.f, 0.f);
            if (gc + 3 < Nd) {
                wv = *(const float4*)&wr[gc];
            } else {
                if (gc + 0 < Nd) wv.x = wr[gc + 0];
                if (gc + 1 < Nd) wv.y = wr[gc + 1];
                if (gc + 2 < Nd) wv.z = wr[gc + 2];
                if (gc + 3 < Nd) wv.w = wr[gc + 3];
            }
            *(float4*)&Ws[wk][wn] = wv;
        }
        __syncthreads();
#pragma unroll
        for (int kk = 0; kk < 16; kk++) {
            float4 a4 = *(float4*)&As[kk][ty * 4];
            float4 b4 = *(float4*)&Ws[kk][tx * 4];
            float av[4] = {a4.x, a4.y, a4.z, a4.w};
            float bv[4] = {b4.x, b4.y, b4.z, b4.w};
#pragma unroll
            for (int i = 0; i < 4; i++)
#pragma unroll
                for (int j = 0; j < 4; j++)
                    acc[i][j] = fmaf(av[i], bv[j], acc[i][j]);
        }
        __syncthreads();
    }

#pragma unroll
    for (int i = 0; i < 4; i++) {
        int r = row0 + ty * 4 + i;
        if (r >= M) continue;
#pragma unroll
        for (int j = 0; j < 4; j++) {
            int c = col0 + tx * 4 + j;
            if (c >= Nd) continue;
            float v = acc[i][j] + bias[c];
            if (RES) v += resid[(size_t)r * Nd + c];
            if (ACT == 1) v = fmaxf(v, 0.f);
            C[(size_t)r * Nd + c] = v;
        }
    }
}

// FV += gcn + cs_emb[cidx] + un_emb[uidx]   (one block per node row)
__global__ __launch_bounds__(256) void add_misc(
    float* __restrict__ FV, const float* __restrict__ gcn,
    const float* __restrict__ cs_emb, const float* __restrict__ un_emb,
    const int* __restrict__ cidx, const int* __restrict__ uidx)
{
    const int n = blockIdx.x, t = threadIdx.x;
    const size_t o = (size_t)n * DIM + t;
    FV[o] += gcn[o] + cs_emb[(size_t)cidx[n] * DIM + t] + un_emb[(size_t)uidx[n] * DIM + t];
}

// Stage 1 fused: per hyperedge, attend over De=32 member nodes; out = LN1(h_e + efeat)
__global__ __launch_bounds__(256) void edge_attn(
    const float* __restrict__ KN, const float* __restrict__ VN,
    const float* __restrict__ QE, const float* __restrict__ efeat,
    const int* __restrict__ e2n, const float* __restrict__ cent1,
    const float* __restrict__ g, const float* __restrict__ bb,
    float* __restrict__ XE)
{
    const int e = blockIdx.x;
    const int t = threadIdx.x, lane = t & 63, w = t >> 6;
    __shared__ float q[QDIM];
    __shared__ int rows[DE];
    __shared__ float sc[DE];
    __shared__ float red[4];

    q[t] = QE[(size_t)e * QDIM + t];
    if (t < DE) rows[t] = e2n[(size_t)e * DE + t];
    __syncthreads();

    float4 qv = *(const float4*)&q[lane * 4];
#pragma unroll
    for (int i = 0; i < DE / 4; i++) {  // 8 dots per wave
        int d = w * (DE / 4) + i;
        const float* kr = KN + (size_t)rows[d] * QDIM;
        float4 kv = *(const float4*)&kr[lane * 4];
        float p = fmaf(kv.x, qv.x, fmaf(kv.y, qv.y, fmaf(kv.z, qv.z, kv.w * qv.w)));
        p = wave_sum(p);
        if (lane == 0) sc[d] = p;
    }
    __syncthreads();
    if (t < DE) {
        float a = sc[t];
        a = (a > 0.f ? a : 0.01f * a) * ATT_SCALE + cent1[(size_t)e * DE + t];
        sc[t] = a;
    }
    __syncthreads();
    if (t == 0) {
        float m = -1e30f;
        for (int d = 0; d < DE; d++) m = fmaxf(m, sc[d]);
        float s = 0.f;
        for (int d = 0; d < DE; d++) { float ex = __expf(sc[d] - m); sc[d] = ex; s += ex; }
        float inv = 1.f / s;
        for (int d = 0; d < DE; d++) sc[d] *= inv;
    }
    __syncthreads();

    float acc = 0.f;
#pragma unroll 4
    for (int d = 0; d < DE; d++)
        acc = fmaf(sc[d], VN[(size_t)rows[d] * DIM + t], acc);
    float x = acc + efeat[(size_t)e * DIM + t];

    // LayerNorm over 256
    float s1 = wave_sum(x);
    if (lane == 0) red[w] = s1;
    __syncthreads();
    float mu = (red[0] + red[1] + red[2] + red[3]) * (1.f / DIM);
    __syncthreads();
    float dx = x - mu;
    float s2 = wave_sum(dx * dx);
    if (lane == 0) red[w] = s2;
    __syncthreads();
    float var = (red[0] + red[1] + red[2] + red[3]) * (1.f / DIM);
    XE[(size_t)e * DIM + t] = dx * rsqrtf(var + LN_EPS) * g[t] + bb[t];
}

// Stage 2 fused: per node, attend over Dv=8 incident hyperedges; out = LN2(h_v + FV)
__global__ __launch_bounds__(256) void node_attn(
    const float* __restrict__ KE, const float* __restrict__ VE,
    const float* __restrict__ QV, const float* __restrict__ FV,
    const int* __restrict__ n2e, const float* __restrict__ cent2,
    const float* __restrict__ g, const float* __restrict__ bb,
    float* __restrict__ XV)
{
    const int n = blockIdx.x;
    const int t = threadIdx.x, lane = t & 63, w = t >> 6;
    __shared__ float q[QDIM];
    __shared__ int rows[DV];
    __shared__ float sc[DV];
    __shared__ float red[4];

    q[t] = QV[(size_t)n * QDIM + t];
    if (t < DV) rows[t] = n2e[(size_t)n * DV + t];
    __syncthreads();

    float4 qv = *(const float4*)&q[lane * 4];
#pragma unroll
    for (int i = 0; i < DV / 4; i++) {  // 2 dots per wave
        int d = w * (DV / 4) + i;
        const float* kr = KE + (size_t)rows[d] * QDIM;
        float4 kv = *(const float4*)&kr[lane * 4];
        float p = fmaf(kv.x, qv.x, fmaf(kv.y, qv.y, fmaf(kv.z, qv.z, kv.w * qv.w)));
        p = wave_sum(p);
        if (lane == 0) sc[d] = p;
    }
    __syncthreads();
    if (t < DV) {
        float a = sc[t];
        a = (a > 0.f ? a : 0.01f * a) * ATT_SCALE + cent2[(size_t)n * DV + t];
        sc[t] = a;
    }
    __syncthreads();
    if (t == 0) {
        float m = -1e30f;
        for (int d = 0; d < DV; d++) m = fmaxf(m, sc[d]);
        float s = 0.f;
        for (int d = 0; d < DV; d++) { float ex = __expf(sc[d] - m); sc[d] = ex; s += ex; }
        float inv = 1.f / s;
        for (int d = 0; d < DV; d++) sc[d] *= inv;
    }
    __syncthreads();

    float acc = 0.f;
#pragma unroll
    for (int d = 0; d < DV; d++)
        acc = fmaf(sc[d], VE[(size_t)rows[d] * DIM + t], acc);
    float x = acc + FV[(size_t)n * DIM + t];

    float s1 = wave_sum(x);
    if (lane == 0) red[w] = s1;
    __syncthreads();
    float mu = (red[0] + red[1] + red[2] + red[3]) * (1.f / DIM);
    __syncthreads();
    float dx = x - mu;
    float s2 = wave_sum(dx * dx);
    if (lane == 0) red[w] = s2;
    __syncthreads();
    float var = (red[0] + red[1] + red[2] + red[3]) * (1.f / DIM);
    XV[(size_t)n * DIM + t] = dx * rsqrtf(var + LN_EPS) * g[t] + bb[t];
}

// Row LayerNorm (in-place safe): one block per row of 256
__global__ __launch_bounds__(256) void ln_rows(
    const float* __restrict__ X, const float* __restrict__ g,
    const float* __restrict__ bb, float* __restrict__ Y)
{
    const int row = blockIdx.x;
    const int t = threadIdx.x, lane = t & 63, w = t >> 6;
    __shared__ float red[4];
    float x = X[(size_t)row * DIM + t];
    float s1 = wave_sum(x);
    if (lane == 0) red[w] = s1;
    __syncthreads();
    float mu = (red[0] + red[1] + red[2] + red[3]) * (1.f / DIM);
    __syncthreads();
    float dx = x - mu;
    float s2 = wave_sum(dx * dx);
    if (lane == 0) red[w] = s2;
    __syncthreads();
    float var = (red[0] + red[1] + red[2] + red[3]) * (1.f / DIM);
    Y[(size_t)row * DIM + t] = dx * rsqrtf(var + LN_EPS) * g[t] + bb[t];
}

extern "C" void kernel_launch(void* const* d_in, const int* in_sizes, int n_in,
                              void* d_out, int out_size, void* d_ws, size_t ws_size,
                              hipStream_t stream)
{
    const float* vfeat  = (const float*)d_in[0];
    const float* efeat  = (const float*)d_in[1];
    const float* eign   = (const float*)d_in[2];
    const float* gcn    = (const float*)d_in[3];
    const float* cent1  = (const float*)d_in[4];
    const float* cent2  = (const float*)d_in[5];
    const int*   cidx   = (const int*)d_in[6];
    const int*   uidx   = (const int*)d_in[7];
    const int*   e2n    = (const int*)d_in[8];
    const int*   n2e    = (const int*)d_in[9];
    const float* W_vtx  = (const float*)d_in[10]; const float* b_vtx = (const float*)d_in[11];
    const float* W_pe   = (const float*)d_in[12]; const float* b_pe  = (const float*)d_in[13];
    const float* cs_emb = (const float*)d_in[14]; const float* un_emb= (const float*)d_in[15];
    const float* W_kv   = (const float*)d_in[16]; const float* b_kv  = (const float*)d_in[17];
    const float* W_vv   = (const float*)d_in[18]; const float* b_vv  = (const float*)d_in[19];
    const float* W_qe   = (const float*)d_in[20]; const float* b_qe  = (const float*)d_in[21];
    const float* W_ke   = (const float*)d_in[22]; const float* b_ke  = (const float*)d_in[23];
    const float* W_ve   = (const float*)d_in[24]; const float* b_ve  = (const float*)d_in[25];
    const float* W_qv   = (const float*)d_in[26]; const float* b_qv  = (const float*)d_in[27];
    const float* W_l1   = (const float*)d_in[28]; const float* b_l1  = (const float*)d_in[29];
    const float* W_l2   = (const float*)d_in[30]; const float* b_l2  = (const float*)d_in[31];
    const float* W_l3   = (const float*)d_in[32]; const float* b_l3  = (const float*)d_in[33];
    const float* W_l4   = (const float*)d_in[34]; const float* b_l4  = (const float*)d_in[35];
    const float* ln1_g  = (const float*)d_in[36]; const float* ln1_b = (const float*)d_in[37];
    const float* ln2_g  = (const float*)d_in[38]; const float* ln2_b = (const float*)d_in[39];
    const float* W_cls  = (const float*)d_in[40]; const float* b_cls = (const float*)d_in[41];
    float* out = (float*)d_out;

    // Workspace layout (f32): 3 N-buffers (reused) + 6 E-buffers = 172 MB
    const size_t NDsz = (size_t)N_NODES * DIM;  // 10,240,000
    const size_t EDsz = (size_t)N_EDGES * DIM;  //  2,048,000
    float* ws = (float*)d_ws;
    float* B0 = ws;            // FV, later TV
    float* B1 = B0 + NDsz;     // KN, later QV, later FVpre/final feat_v
    float* B2 = B1 + NDsz;     // VN, later XV
    float* QE = B2 + NDsz;
    float* XE = QE + EDsz;
    float* TE = XE + EDsz;
    float* FE = TE + EDsz;
    float* KE = FE + EDsz;
    float* VE = KE + EDsz;

    const dim3 blk(256);
    const dim3 gN(DIM / 64, N_NODES / 64);   // 4 x 625
    const dim3 gE(DIM / 64, N_EDGES / 64);   // 4 x 125
    const dim3 gC(1, N_NODES / 64);          // classifier: Nd=40 -> 1 col tile

    // ---- feature assembly ----
    gemm_f32<0, false><<<gN, blk, 0, stream>>>(vfeat, W_vtx, b_vtx, nullptr, B0, N_NODES, DIM, DIM);
    gemm_f32<0, true ><<<gN, blk, 0, stream>>>(eign, W_pe, b_pe, B0, B0, N_NODES, EIGD, DIM);
    add_misc<<<N_NODES, blk, 0, stream>>>(B0, gcn, cs_emb, un_emb, cidx, uidx);

    // ---- stage 1: hyperedges attend over member nodes ----
    gemm_f32<0, false><<<gN, blk, 0, stream>>>(B0, W_kv, b_kv, nullptr, B1, N_NODES, DIM, QDIM);  // k_n
    gemm_f32<0, false><<<gN, blk, 0, stream>>>(B0, W_vv, b_vv, nullptr, B2, N_NODES, DIM, DIM);   // v_n
    gemm_f32<0, false><<<gE, blk, 0, stream>>>(efeat, W_qe, b_qe, nullptr, QE, N_EDGES, DIM, QDIM); // q_e
    edge_attn<<<N_EDGES, blk, 0, stream>>>(B1, B2, QE, efeat, e2n, cent1, ln1_g, ln1_b, XE);
    gemm_f32<1, false><<<gE, blk, 0, stream>>>(XE, W_l1, b_l1, nullptr, TE, N_EDGES, DIM, QDIM);  // relu(l1)
    gemm_f32<0, true ><<<gE, blk, 0, stream>>>(TE, W_l2, b_l2, XE, FE, N_EDGES, QDIM, DIM);       // + x_e
    ln_rows<<<N_EDGES, blk, 0, stream>>>(FE, ln1_g, ln1_b, FE);                                   // feat_e

    // ---- stage 2: nodes attend over incident hyperedges ----
    gemm_f32<0, false><<<gE, blk, 0, stream>>>(FE, W_ke, b_ke, nullptr, KE, N_EDGES, DIM, QDIM);  // k_e
    gemm_f32<0, false><<<gE, blk, 0, stream>>>(FE, W_ve, b_ve, nullptr, VE, N_EDGES, DIM, DIM);   // v_e
    gemm_f32<0, false><<<gN, blk, 0, stream>>>(B0, W_qv, b_qv, nullptr, B1, N_NODES, DIM, QDIM);  // q_v
    node_attn<<<N_NODES, blk, 0, stream>>>(KE, VE, B1, B0, n2e, cent2, ln2_g, ln2_b, B2);         // x_v
    gemm_f32<1, false><<<gN, blk, 0, stream>>>(B2, W_l3, b_l3, nullptr, B0, N_NODES, DIM, QDIM);  // relu(l3)
    gemm_f32<0, true ><<<gN, blk, 0, stream>>>(B0, W_l4, b_l4, B2, B1, N_NODES, QDIM, DIM);       // + x_v
    ln_rows<<<N_NODES, blk, 0, stream>>>(B1, ln2_g, ln2_b, B1);                                   // feat_v

    // ---- classifier head ----
    gemm_f32<0, false><<<gC, blk, 0, stream>>>(B1, W_cls, b_cls, nullptr, out, N_NODES, DIM, NCLS);
}

// Round 2
// 505.565 us; speedup vs baseline: 1.8755x; 1.8755x over previous
//
// R1: bf16 MFMA GEMMs (16x16x32, f32 acc) + bf16 intermediates everywhere.
// - one batched transpose-cast kernel prepares Wt[n][k] bf16 for all 13 weights
// - gemm_mfma: 128x128 tile, BK=64, 4 waves, XOR-swizzled LDS (both sides),
//   fused epilogues (bias/relu/residual/assembly/classifier)
// - attention + LN kernels read/write bf16, compute f32
#include <hip/hip_runtime.h>
#include <hip/hip_bf16.h>
#include <cstddef>

#define N_NODES 40000
#define N_EDGES 8000
#define DE 32
#define DV 8
#define DIM 256
#define QDIM 256
#define EIGD 64
#define NCLS 40
#define LN_EPS 1e-5f
#define ATT_SCALE 0.0625f   // 1/sqrt(256)

typedef unsigned short u16;
typedef unsigned int u32;
using i16x8 = __attribute__((ext_vector_type(8))) short;
using f32x4 = __attribute__((ext_vector_type(4))) float;

__device__ inline u16 f2b(float f) {   // RNE f32 -> bf16 bits
    union { float f; u32 u; } c; c.f = f;
    u32 u = c.u + 0x7FFF + ((c.u >> 16) & 1);
    return (u16)(u >> 16);
}
__device__ inline float b2f(u16 b) {
    union { u32 u; float f; } c; c.u = (u32)b << 16;
    return c.f;
}

__device__ inline float wave_sum(float v) {
#pragma unroll
    for (int off = 32; off > 0; off >>= 1) v += __shfl_down(v, off, 64);
    return v;  // valid in lane 0
}

// ---------------------------------------------------------------------------
// Batched transpose-cast: Wt[n][k] = bf16(W[k][n]) for all 13 weight matrices.
// grid (8,8,13), block 256. Each Wt slot is 65536 u16 in the pool.
// ---------------------------------------------------------------------------
__global__ __launch_bounds__(256) void prep_weights(
    const float* w0, const float* w1, const float* w2, const float* w3,
    const float* w4, const float* w5, const float* w6, const float* w7,
    const float* w8, const float* w9, const float* w10, const float* w11,
    const float* w12, u16* __restrict__ pool)
{
    const float* srcs[13] = {w0,w1,w2,w3,w4,w5,w6,w7,w8,w9,w10,w11,w12};
    const int Ks[13]  = {256,64,256,256,256,256,256,256,256,256,256,256,256};
    const int Nds[13] = {256,256,256,256,256,256,256,256,256,256,256,256,40};
    const int id = blockIdx.z;
    const float* W = srcs[id];
    u16* Wt = pool + (size_t)id * 65536;
    const int K = Ks[id], Nd = Nds[id];
    const int k0 = blockIdx.x * 32, n0 = blockIdx.y * 32;
    if (k0 >= K || n0 >= Nd) return;

    __shared__ float tile[32][33];
    const int x = threadIdx.x & 31, y4 = (threadIdx.x >> 5) * 4;
#pragma unroll
    for (int j = 0; j < 4; j++) {
        int k = k0 + y4 + j;
        tile[y4 + j][x] = (k < K && (n0 + x) < Nd) ? W[(size_t)k * Nd + n0 + x] : 0.f;
    }
    __syncthreads();
#pragma unroll
    for (int j = 0; j < 4; j++) {
        int n = n0 + y4 + j;
        if (n < Nd && (k0 + x) < K)
            Wt[(size_t)n * K + k0 + x] = f2b(tile[x][y4 + j]);
    }
}

// ---------------------------------------------------------------------------
// bf16 MFMA GEMM: C[M,Nd] = epi(A[M,K] @ Wt[Nd,K]^T + bias)
// 128x128 tile, BK=64, 256 threads = 4 waves, each wave owns a 64x64 quadrant
// (4x4 fragments of 16x16x32). LDS linear [128][64] u16 with XOR swizzle
// (blk ^= row&7 on 16B blocks) applied on BOTH ds_write and ds_read.
// EPI: 0 = bias->bf16; 1 = relu(bias)->bf16; 2 = bias+resid->bf16;
//      3 = bias+resid+gcn+emb1[idx1]+emb2[idx2]->bf16 (feature assembly);
//      4 = bias->f32 with col guard (classifier).
// AF32: A is f32 (cast during staging) else bf16.
// ---------------------------------------------------------------------------
template <bool AF32, int EPI>
__global__ __launch_bounds__(256) void gemm_mfma(
    const void* __restrict__ Av, const u16* __restrict__ Wt,
    const float* __restrict__ bias, const u16* __restrict__ resid,
    const float* __restrict__ gcn, const float* __restrict__ emb1,
    const float* __restrict__ emb2, const int* __restrict__ idx1,
    const int* __restrict__ idx2,
    void* __restrict__ Cv, int M, int K, int Nd)
{
    __shared__ u16 Asm[128 * 64];
    __shared__ u16 Bsm[128 * 64];
    const int t = threadIdx.x;
    const int lane = t & 63, w = t >> 6;
    const int wr = w >> 1, wc = w & 1;
    const int row0 = blockIdx.y * 128, col0 = blockIdx.x * 128;

    f32x4 acc[4][4] = {};

    const int sr = t >> 1;          // staging row 0..127
    const int sb0 = (t & 1) * 4;    // staging 16B-block base (0 or 4)
    const int ssw = sr & 7;         // staging swizzle

    const int fr = lane & 15, h = lane >> 4;
    const int lsw = fr & 7;         // fragment-read swizzle (row&7 == fr&7)

    for (int k0 = 0; k0 < K; k0 += 64) {
        {   // stage A tile (rows clamped; OOB rows produce discarded C rows)
            int rg = row0 + sr; if (rg > M - 1) rg = M - 1;
            if constexpr (AF32) {
                const float* Ap = (const float*)Av + (size_t)rg * K + k0 + sb0 * 8;
#pragma unroll
                for (int i = 0; i < 4; i++) {
                    float4 f0 = *(const float4*)(Ap + i * 8);
                    float4 f1 = *(const float4*)(Ap + i * 8 + 4);
                    i16x8 v;
                    v[0] = (short)f2b(f0.x); v[1] = (short)f2b(f0.y);
                    v[2] = (short)f2b(f0.z); v[3] = (short)f2b(f0.w);
                    v[4] = (short)f2b(f1.x); v[5] = (short)f2b(f1.y);
                    v[6] = (short)f2b(f1.z); v[7] = (short)f2b(f1.w);
                    *(i16x8*)&Asm[sr * 64 + ((sb0 + i) ^ ssw) * 8] = v;
                }
            } else {
                const u16* Ap = (const u16*)Av + (size_t)rg * K + k0 + sb0 * 8;
#pragma unroll
                for (int i = 0; i < 4; i++)
                    *(i16x8*)&Asm[sr * 64 + ((sb0 + i) ^ ssw) * 8] =
                        *(const i16x8*)(Ap + i * 8);
            }
        }
        {   // stage Wt tile (rows are output cols; clamp for Nd<128)
            int ng = col0 + sr; if (ng > Nd - 1) ng = Nd - 1;
            const u16* Bp = Wt + (size_t)ng * K + k0 + sb0 * 8;
#pragma unroll
            for (int i = 0; i < 4; i++)
                *(i16x8*)&Bsm[sr * 64 + ((sb0 + i) ^ ssw) * 8] =
                    *(const i16x8*)(Bp + i * 8);
        }
        __syncthreads();
#pragma unroll
        for (int kk = 0; kk < 2; kk++) {
            i16x8 af[4], bfr[4];
#pragma unroll
            for (int m = 0; m < 4; m++)
                af[m] = *(i16x8*)&Asm[(wr * 64 + m * 16 + fr) * 64 +
                                      ((kk * 4 + h) ^ lsw) * 8];
#pragma unroll
            for (int n = 0; n < 4; n++)
                bfr[n] = *(i16x8*)&Bsm[(wc * 64 + n * 16 + fr) * 64 +
                                       ((kk * 4 + h) ^ lsw) * 8];
#pragma unroll
            for (int m = 0; m < 4; m++)
#pragma unroll
                for (int n = 0; n < 4; n++)
                    acc[m][n] = __builtin_amdgcn_mfma_f32_16x16x32_bf16(
                        af[m], bfr[n], acc[m][n], 0, 0, 0);
        }
        __syncthreads();
    }

    // epilogue: C/D layout col = lane&15, row = (lane>>4)*4 + j  [m89]
#pragma unroll
    for (int m = 0; m < 4; m++) {
#pragma unroll
        for (int j = 0; j < 4; j++) {
            const int grow = row0 + wr * 64 + m * 16 + h * 4 + j;
            if (grow >= M) continue;
            int i1 = 0, i2 = 0;
            if constexpr (EPI == 3) { i1 = idx1[grow]; i2 = idx2[grow]; }
#pragma unroll
            for (int n = 0; n < 4; n++) {
                const int gcol = col0 + wc * 64 + n * 16 + fr;
                if (gcol >= Nd) continue;
                float v = acc[m][n][j] + bias[gcol];
                if constexpr (EPI == 1) v = fmaxf(v, 0.f);
                if constexpr (EPI == 2)
                    v += b2f(resid[(size_t)grow * Nd + gcol]);
                if constexpr (EPI == 3) {
                    v += b2f(resid[(size_t)grow * Nd + gcol]);
                    v += gcn[(size_t)grow * Nd + gcol];
                    v += emb1[(size_t)i1 * Nd + gcol];
                    v += emb2[(size_t)i2 * Nd + gcol];
                }
                if constexpr (EPI == 4)
                    ((float*)Cv)[(size_t)grow * Nd + gcol] = v;
                else
                    ((u16*)Cv)[(size_t)grow * Nd + gcol] = f2b(v);
            }
        }
    }
}

// ---------------------------------------------------------------------------
// Stage 1 fused: per hyperedge attend over De=32 member nodes; LN1(h_e+efeat)
// ---------------------------------------------------------------------------
__global__ __launch_bounds__(256) void edge_attn(
    const u16* __restrict__ KN, const u16* __restrict__ VN,
    const u16* __restrict__ QE, const float* __restrict__ efeat,
    const int* __restrict__ e2n, const float* __restrict__ cent1,
    const float* __restrict__ g, const float* __restrict__ bb,
    u16* __restrict__ XE)
{
    const int e = blockIdx.x;
    const int t = threadIdx.x, lane = t & 63, w = t >> 6;
    __shared__ float q[QDIM];
    __shared__ int rows[DE];
    __shared__ float sc[DE];
    __shared__ float red[4];

    q[t] = b2f(QE[(size_t)e * QDIM + t]);
    if (t < DE) rows[t] = e2n[(size_t)e * DE + t];
    __syncthreads();

    float4 qv = *(const float4*)&q[lane * 4];
#pragma unroll
    for (int i = 0; i < DE / 4; i++) {  // 8 dots per wave
        int d = w * (DE / 4) + i;
        const u16* kr = KN + (size_t)rows[d] * QDIM + lane * 4;
        ushort4 k4 = *(const ushort4*)kr;
        float p = qv.x * b2f(k4.x) + qv.y * b2f(k4.y)
                + qv.z * b2f(k4.z) + qv.w * b2f(k4.w);
        p = wave_sum(p);
        if (lane == 0) sc[d] = p;
    }
    __syncthreads();
    if (t < DE) {
        float a = sc[t];
        a = (a > 0.f ? a : 0.01f * a) * ATT_SCALE + cent1[(size_t)e * DE + t];
        sc[t] = a;
    }
    __syncthreads();
    if (t == 0) {
        float m = -1e30f;
        for (int d = 0; d < DE; d++) m = fmaxf(m, sc[d]);
        float s = 0.f;
        for (int d = 0; d < DE; d++) { float ex = __expf(sc[d] - m); sc[d] = ex; s += ex; }
        float inv = 1.f / s;
        for (int d = 0; d < DE; d++) sc[d] *= inv;
    }
    __syncthreads();

    float acc = 0.f;
#pragma unroll 4
    for (int d = 0; d < DE; d++)
        acc = fmaf(sc[d], b2f(VN[(size_t)rows[d] * DIM + t]), acc);
    float x = acc + efeat[(size_t)e * DIM + t];

    float s1 = wave_sum(x);
    if (lane == 0) red[w] = s1;
    __syncthreads();
    float mu = (red[0] + red[1] + red[2] + red[3]) * (1.f / DIM);
    __syncthreads();
    float dx = x - mu;
    float s2 = wave_sum(dx * dx);
    if (lane == 0) red[w] = s2;
    __syncthreads();
    float var = (red[0] + red[1] + red[2] + red[3]) * (1.f / DIM);
    XE[(size_t)e * DIM + t] = f2b(dx * rsqrtf(var + LN_EPS) * g[t] + bb[t]);
}

// ---------------------------------------------------------------------------
// Stage 2 fused: per node attend over Dv=8 incident hyperedges; LN2(h_v+FV)
// ---------------------------------------------------------------------------
__global__ __launch_bounds__(256) void node_attn(
    const u16* __restrict__ KE, const u16* __restrict__ VE,
    const u16* __restrict__ QV, const u16* __restrict__ FV,
    const int* __restrict__ n2e, const float* __restrict__ cent2,
    const float* __restrict__ g, const float* __restrict__ bb,
    u16* __restrict__ XV)
{
    const int n = blockIdx.x;
    const int t = threadIdx.x, lane = t & 63, w = t >> 6;
    __shared__ float q[QDIM];
    __shared__ int rows[DV];
    __shared__ float sc[DV];
    __shared__ float red[4];

    q[t] = b2f(QV[(size_t)n * QDIM + t]);
    if (t < DV) rows[t] = n2e[(size_t)n * DV + t];
    __syncthreads();

    float4 qv = *(const float4*)&q[lane * 4];
#pragma unroll
    for (int i = 0; i < DV / 4; i++) {  // 2 dots per wave
        int d = w * (DV / 4) + i;
        const u16* kr = KE + (size_t)rows[d] * QDIM + lane * 4;
        ushort4 k4 = *(const ushort4*)kr;
        float p = qv.x * b2f(k4.x) + qv.y * b2f(k4.y)
                + qv.z * b2f(k4.z) + qv.w * b2f(k4.w);
        p = wave_sum(p);
        if (lane == 0) sc[d] = p;
    }
    __syncthreads();
    if (t < DV) {
        float a = sc[t];
        a = (a > 0.f ? a : 0.01f * a) * ATT_SCALE + cent2[(size_t)n * DV + t];
        sc[t] = a;
    }
    __syncthreads();
    if (t == 0) {
        float m = -1e30f;
        for (int d = 0; d < DV; d++) m = fmaxf(m, sc[d]);
        float s = 0.f;
        for (int d = 0; d < DV; d++) { float ex = __expf(sc[d] - m); sc[d] = ex; s += ex; }
        float inv = 1.f / s;
        for (int d = 0; d < DV; d++) sc[d] *= inv;
    }
    __syncthreads();

    float acc = 0.f;
#pragma unroll
    for (int d = 0; d < DV; d++)
        acc = fmaf(sc[d], b2f(VE[(size_t)rows[d] * DIM + t]), acc);
    float x = acc + b2f(FV[(size_t)n * DIM + t]);

    float s1 = wave_sum(x);
    if (lane == 0) red[w] = s1;
    __syncthreads();
    float mu = (red[0] + red[1] + red[2] + red[3]) * (1.f / DIM);
    __syncthreads();
    float dx = x - mu;
    float s2 = wave_sum(dx * dx);
    if (lane == 0) red[w] = s2;
    __syncthreads();
    float var = (red[0] + red[1] + red[2] + red[3]) * (1.f / DIM);
    XV[(size_t)n * DIM + t] = f2b(dx * rsqrtf(var + LN_EPS) * g[t] + bb[t]);
}

// Row LayerNorm, bf16 in/out (in-place safe)
__global__ __launch_bounds__(256) void ln_rows(
    const u16* __restrict__ X, const float* __restrict__ g,
    const float* __restrict__ bb, u16* __restrict__ Y)
{
    const int row = blockIdx.x;
    const int t = threadIdx.x, lane = t & 63, w = t >> 6;
    __shared__ float red[4];
    float x = b2f(X[(size_t)row * DIM + t]);
    float s1 = wave_sum(x);
    if (lane == 0) red[w] = s1;
    __syncthreads();
    float mu = (red[0] + red[1] + red[2] + red[3]) * (1.f / DIM);
    __syncthreads();
    float dx = x - mu;
    float s2 = wave_sum(dx * dx);
    if (lane == 0) red[w] = s2;
    __syncthreads();
    float var = (red[0] + red[1] + red[2] + red[3]) * (1.f / DIM);
    Y[(size_t)row * DIM + t] = f2b(dx * rsqrtf(var + LN_EPS) * g[t] + bb[t]);
}

extern "C" void kernel_launch(void* const* d_in, const int* in_sizes, int n_in,
                              void* d_out, int out_size, void* d_ws, size_t ws_size,
                              hipStream_t stream)
{
    const float* vfeat  = (const float*)d_in[0];
    const float* efeat  = (const float*)d_in[1];
    const float* eign   = (const float*)d_in[2];
    const float* gcn    = (const float*)d_in[3];
    const float* cent1  = (const float*)d_in[4];
    const float* cent2  = (const float*)d_in[5];
    const int*   cidx   = (const int*)d_in[6];
    const int*   uidx   = (const int*)d_in[7];
    const int*   e2n    = (const int*)d_in[8];
    const int*   n2e    = (const int*)d_in[9];
    const float* W_vtx  = (const float*)d_in[10]; const float* b_vtx = (const float*)d_in[11];
    const float* W_pe   = (const float*)d_in[12]; const float* b_pe  = (const float*)d_in[13];
    const float* cs_emb = (const float*)d_in[14]; const float* un_emb= (const float*)d_in[15];
    const float* W_kv   = (const float*)d_in[16]; const float* b_kv  = (const float*)d_in[17];
    const float* W_vv   = (const float*)d_in[18]; const float* b_vv  = (const float*)d_in[19];
    const float* W_qe   = (const float*)d_in[20]; const float* b_qe  = (const float*)d_in[21];
    const float* W_ke   = (const float*)d_in[22]; const float* b_ke  = (const float*)d_in[23];
    const float* W_ve   = (const float*)d_in[24]; const float* b_ve  = (const float*)d_in[25];
    const float* W_qv   = (const float*)d_in[26]; const float* b_qv  = (const float*)d_in[27];
    const float* W_l1   = (const float*)d_in[28]; const float* b_l1  = (const float*)d_in[29];
    const float* W_l2   = (const float*)d_in[30]; const float* b_l2  = (const float*)d_in[31];
    const float* W_l3   = (const float*)d_in[32]; const float* b_l3  = (const float*)d_in[33];
    const float* W_l4   = (const float*)d_in[34]; const float* b_l4  = (const float*)d_in[35];
    const float* ln1_g  = (const float*)d_in[36]; const float* ln1_b = (const float*)d_in[37];
    const float* ln2_g  = (const float*)d_in[38]; const float* ln2_b = (const float*)d_in[39];
    const float* W_cls  = (const float*)d_in[40]; const float* b_cls = (const float*)d_in[41];
    float* out = (float*)d_out;

    // bf16 workspace: 3 N-buffers + 6 E-buffers + 13-slot Wt pool (~88 MB)
    const size_t NE = (size_t)N_NODES * DIM;  // 10,240,000
    const size_t EE = (size_t)N_EDGES * DIM;  //  2,048,000
    u16* ws = (u16*)d_ws;
    u16* FV = ws;            // assembled feat_v (lives to the end)
    u16* T0 = FV + NE;       // lin1 -> KN -> QV -> TV
    u16* B2 = T0 + NE;       // VN -> XV
    u16* QE = B2 + NE;
    u16* XE = QE + EE;
    u16* TE = XE + EE;
    u16* FE = TE + EE;       // FFN-out -> feat_e (LN in place)
    u16* KE = FE + EE;
    u16* VE = KE + EE;
    u16* Wp = VE + EE;       // 13 * 65536 u16
    u16* Wt_vtx = Wp +  0*65536; u16* Wt_pe = Wp +  1*65536;
    u16* Wt_kv  = Wp +  2*65536; u16* Wt_vv = Wp +  3*65536;
    u16* Wt_qe  = Wp +  4*65536; u16* Wt_ke = Wp +  5*65536;
    u16* Wt_ve  = Wp +  6*65536; u16* Wt_qv = Wp +  7*65536;
    u16* Wt_l1  = Wp +  8*65536; u16* Wt_l2 = Wp +  9*65536;
    u16* Wt_l3  = Wp + 10*65536; u16* Wt_l4 = Wp + 11*65536;
    u16* Wt_cls = Wp + 12*65536;

    const dim3 blk(256);
    const dim3 gW(8, 8, 13);
    const dim3 gN(2, (N_NODES + 127) / 128);   // (2, 313)
    const dim3 gE(2, (N_EDGES + 127) / 128);   // (2, 63)
    const dim3 gC(1, (N_NODES + 127) / 128);   // classifier

    prep_weights<<<gW, blk, 0, stream>>>(
        W_vtx, W_pe, W_kv, W_vv, W_qe, W_ke, W_ve, W_qv,
        W_l1, W_l2, W_l3, W_l4, W_cls, Wp);

    // ---- feature assembly ----
    gemm_mfma<true, 0><<<gN, blk, 0, stream>>>(vfeat, Wt_vtx, b_vtx,
        nullptr, nullptr, nullptr, nullptr, nullptr, nullptr, T0, N_NODES, DIM, DIM);
    gemm_mfma<true, 3><<<gN, blk, 0, stream>>>(eign, Wt_pe, b_pe,
        T0, gcn, cs_emb, un_emb, cidx, uidx, FV, N_NODES, EIGD, DIM);

    // ---- stage 1: hyperedges attend over member nodes ----
    gemm_mfma<false, 0><<<gN, blk, 0, stream>>>(FV, Wt_kv, b_kv,
        nullptr, nullptr, nullptr, nullptr, nullptr, nullptr, T0, N_NODES, DIM, QDIM); // k_n
    gemm_mfma<false, 0><<<gN, blk, 0, stream>>>(FV, Wt_vv, b_vv,
        nullptr, nullptr, nullptr, nullptr, nullptr, nullptr, B2, N_NODES, DIM, DIM);  // v_n
    gemm_mfma<true, 0><<<gE, blk, 0, stream>>>(efeat, Wt_qe, b_qe,
        nullptr, nullptr, nullptr, nullptr, nullptr, nullptr, QE, N_EDGES, DIM, QDIM); // q_e
    edge_attn<<<N_EDGES, blk, 0, stream>>>(T0, B2, QE, efeat, e2n, cent1, ln1_g, ln1_b, XE);
    gemm_mfma<false, 1><<<gE, blk, 0, stream>>>(XE, Wt_l1, b_l1,
        nullptr, nullptr, nullptr, nullptr, nullptr, nullptr, TE, N_EDGES, DIM, QDIM); // relu(l1)
    gemm_mfma<false, 2><<<gE, blk, 0, stream>>>(TE, Wt_l2, b_l2,
        XE, nullptr, nullptr, nullptr, nullptr, nullptr, FE, N_EDGES, QDIM, DIM);      // + x_e
    ln_rows<<<N_EDGES, blk, 0, stream>>>(FE, ln1_g, ln1_b, FE);                        // feat_e

    // ---- stage 2: nodes attend over incident hyperedges ----
    gemm_mfma<false, 0><<<gE, blk, 0, stream>>>(FE, Wt_ke, b_ke,
        nullptr, nullptr, nullptr, nullptr, nullptr, nullptr, KE, N_EDGES, DIM, QDIM); // k_e
    gemm_mfma<false, 0><<<gE, blk, 0, stream>>>(FE, Wt_ve, b_ve,
        nullptr, nullptr, nullptr, nullptr, nullptr, nullptr, VE, N_EDGES, DIM, DIM);  // v_e
    gemm_mfma<false, 0><<<gN, blk, 0, stream>>>(FV, Wt_qv, b_qv,
        nullptr, nullptr, nullptr, nullptr, nullptr, nullptr, T0, N_NODES, DIM, QDIM); // q_v
    node_attn<<<N_NODES, blk, 0, stream>>>(KE, VE, T0, FV, n2e, cent2, ln2_g, ln2_b, B2);
    gemm_mfma<false, 1><<<gN, blk, 0, stream>>>(B2, Wt_l3, b_l3,
        nullptr, nullptr, nullptr, nullptr, nullptr, nullptr, T0, N_NODES, DIM, QDIM); // relu(l3)
    gemm_mfma<false, 2><<<gN, blk, 0, stream>>>(T0, Wt_l4, b_l4,
        B2, nullptr, nullptr, nullptr, nullptr, nullptr, FV, N_NODES, QDIM, DIM);      // + x_v
    ln_rows<<<N_NODES, blk, 0, stream>>>(FV, ln2_g, ln2_b, FV);                        // feat_v

    // ---- classifier head (f32 out, col guard) ----
    gemm_mfma<false, 4><<<gC, blk, 0, stream>>>(FV, Wt_cls, b_cls,
        nullptr, nullptr, nullptr, nullptr, nullptr, nullptr, out, N_NODES, DIM, NCLS);
}

// Round 3
// 269.299 us; speedup vs baseline: 3.5209x; 1.8773x over previous
//
// R2: pipelined GEMM (global_load_lds + dbuf + counted vmcnt + raw barriers),
// fused K/V weight GEMMs (Nd=512), bf16 pre-cast of f32 activations,
// wave-per-row attention/LN (no LDS, no __syncthreads).
#include <hip/hip_runtime.h>
#include <hip/hip_bf16.h>
#include <cstddef>

#define N_NODES 40000
#define N_EDGES 8000
#define DE 32
#define DV 8
#define DIM 256
#define QDIM 256
#define EIGD 64
#define NCLS 40
#define LN_EPS 1e-5f
#define ATT_SCALE 0.0625f   // 1/sqrt(256)

typedef unsigned short u16;
typedef unsigned int u32;
using i16x8 = __attribute__((ext_vector_type(8))) short;
using f32x4 = __attribute__((ext_vector_type(4))) float;

__device__ inline u16 f2b(float f) {   // RNE f32 -> bf16 bits
    union { float f; u32 u; } c; c.f = f;
    u32 u = c.u + 0x7FFF + ((c.u >> 16) & 1);
    return (u16)(u >> 16);
}
__device__ inline float b2f(u16 b) {
    union { u32 u; float f; } c; c.u = (u32)b << 16;
    return c.f;
}

__device__ inline void gload_lds16(const u16* g, u16* l) {
    __builtin_amdgcn_global_load_lds(
        (const __attribute__((address_space(1))) void*)g,
        (__attribute__((address_space(3))) void*)l, 16, 0, 0);
}

#define VMCNT6 asm volatile("s_waitcnt vmcnt(6)" ::: "memory")
#define VMCNT0 asm volatile("s_waitcnt vmcnt(0)" ::: "memory")
#define LGKM0  asm volatile("s_waitcnt lgkmcnt(0)" ::: "memory")

// ---------------------------------------------------------------------------
// cast f32 -> bf16, 4 elems/thread, grid-stride
// ---------------------------------------------------------------------------
__global__ __launch_bounds__(256) void cast_bf16(
    const float* __restrict__ src, u16* __restrict__ dst, int n4)
{
    for (int i = blockIdx.x * 256 + threadIdx.x; i < n4; i += gridDim.x * 256) {
        float4 v = ((const float4*)src)[i];
        ushort4 o;
        o.x = f2b(v.x); o.y = f2b(v.y); o.z = f2b(v.z); o.w = f2b(v.w);
        ((ushort4*)dst)[i] = o;
    }
}

// ---------------------------------------------------------------------------
// Batched transpose-cast: Wt[n][k] = bf16(W[k][n]) for all 13 weights.
// Slot order: 0 vtx, 1 pe, 2 kv, 3 vv, 4 qe, 5 ke, 6 ve, 7 qv,
//             8 l1, 9 l2, 10 l3, 11 l4, 12 cls.  (kv|vv and ke|ve adjacent
// so a single [512][256] B matrix serves the fused Nd=512 GEMMs.)
// ---------------------------------------------------------------------------
__global__ __launch_bounds__(256) void prep_weights(
    const float* w0, const float* w1, const float* w2, const float* w3,
    const float* w4, const float* w5, const float* w6, const float* w7,
    const float* w8, const float* w9, const float* w10, const float* w11,
    const float* w12, u16* __restrict__ pool)
{
    const float* srcs[13] = {w0,w1,w2,w3,w4,w5,w6,w7,w8,w9,w10,w11,w12};
    const int Ks[13]  = {256,64,256,256,256,256,256,256,256,256,256,256,256};
    const int Nds[13] = {256,256,256,256,256,256,256,256,256,256,256,256,40};
    const int id = blockIdx.z;
    const float* W = srcs[id];
    u16* Wt = pool + (size_t)id * 65536;
    const int K = Ks[id], Nd = Nds[id];
    const int k0 = blockIdx.x * 32, n0 = blockIdx.y * 32;
    if (k0 >= K || n0 >= Nd) return;

    __shared__ float tile[32][33];
    const int x = threadIdx.x & 31, y4 = (threadIdx.x >> 5) * 4;
#pragma unroll
    for (int j = 0; j < 4; j++) {
        int k = k0 + y4 + j;
        tile[y4 + j][x] = (k < K && (n0 + x) < Nd) ? W[(size_t)k * Nd + n0 + x] : 0.f;
    }
    __syncthreads();
#pragma unroll
    for (int j = 0; j < 4; j++) {
        int n = n0 + y4 + j;
        if (n < Nd && (k0 + x) < K)
            Wt[(size_t)n * K + k0 + x] = f2b(tile[x][y4 + j]);
    }
}

// ---------------------------------------------------------------------------
// Pipelined bf16 MFMA GEMM: C[M,Nd] = epi(A[M,K] @ Wt[Nd,K]^T + bias)
// BM=64, BN=128, BK=64. 4 waves (2x2), each owns 32x64 (2x4 fragments).
// Double-buffered LDS via global_load_lds (linear dest, source pre-swizzled,
// read swizzled: involution b ^= row&7 on 16B blocks). 2-phase schedule:
// STAGE(next) -> vmcnt(6) -> barrier -> ds_read -> lgkmcnt(0) -> barrier
// -> MFMA. M must be a multiple of 64.
// EPI: 0 bias->bf16; 1 relu->bf16; 2 +resid->bf16; 3 assembly->bf16;
//      4 bias->f32 (Nd guard).
// ---------------------------------------------------------------------------
template <int EPI>
__global__ __launch_bounds__(256) void gemm_mfma(
    const u16* __restrict__ A, const u16* __restrict__ Wt,
    const float* __restrict__ bias, const float* __restrict__ bias2,
    const u16* __restrict__ resid,
    const float* __restrict__ gcn, const float* __restrict__ emb1,
    const float* __restrict__ emb2, const int* __restrict__ idx1,
    const int* __restrict__ idx2,
    void* __restrict__ Cv, int M, int K, int Nd)
{
    __shared__ u16 Asm[2][64 * 64];
    __shared__ u16 Bsm[2][128 * 64];
    const int t = threadIdx.x;
    const int lane = t & 63, w = t >> 6;
    const int wr = w >> 1, wc = w & 1;
    const int row0 = blockIdx.y * 64, col0 = blockIdx.x * 128;

    f32x4 acc[2][4] = {};

    // staging: dest row group = lane>>3, dest blk = lane&7; source blk is
    // XOR-swizzled so that LDS[row][b] = global[row][b ^ (row&7)]
    const int srow = lane >> 3;
    const int sblk = ((lane & 7) ^ srow) * 8;   // u16 offset within row

    const int fr = lane & 15, h = lane >> 4;
    const int lsw = fr & 7;
    const int nt = K >> 6;

    auto stage = [&](int buf, int kt) {
        const int k0 = kt << 6;
#pragma unroll
        for (int i = 0; i < 2; i++) {           // A: rows w*16 + i*8 (+srow)
            int r = w * 16 + i * 8;
            const u16* gp = A + (size_t)(row0 + r + srow) * K + k0 + sblk;
            gload_lds16(gp, &Asm[buf][r * 64]);
        }
#pragma unroll
        for (int i = 0; i < 4; i++) {           // B: rows w*32 + i*8 (+srow)
            int r = w * 32 + i * 8;
            int ng = col0 + r + srow; if (ng > Nd - 1) ng = Nd - 1;
            const u16* gp = Wt + (size_t)ng * K + k0 + sblk;
            gload_lds16(gp, &Bsm[buf][r * 64]);
        }
    };

    stage(0, 0);
    for (int kt = 0; kt < nt; ++kt) {
        const int cur = kt & 1;
        const bool more = (kt + 1 < nt);
        if (more) stage(cur ^ 1, kt + 1);
        if (more) { VMCNT6; } else { VMCNT0; }
        __builtin_amdgcn_s_barrier();           // buf[cur] fully staged

        i16x8 af[2][2], bf[2][4];
#pragma unroll
        for (int kk = 0; kk < 2; kk++) {
#pragma unroll
            for (int m = 0; m < 2; m++)
                af[kk][m] = *(const i16x8*)&Asm[cur][(wr * 32 + m * 16 + fr) * 64 +
                                                    ((kk * 4 + h) ^ lsw) * 8];
#pragma unroll
            for (int n = 0; n < 4; n++)
                bf[kk][n] = *(const i16x8*)&Bsm[cur][(wc * 64 + n * 16 + fr) * 64 +
                                                    ((kk * 4 + h) ^ lsw) * 8];
        }
        LGKM0;
        __builtin_amdgcn_sched_barrier(0);
        __builtin_amdgcn_s_barrier();           // all waves done reading cur

#pragma unroll
        for (int kk = 0; kk < 2; kk++)
#pragma unroll
            for (int m = 0; m < 2; m++)
#pragma unroll
                for (int n = 0; n < 4; n++)
                    acc[m][n] = __builtin_amdgcn_mfma_f32_16x16x32_bf16(
                        af[kk][m], bf[kk][n], acc[m][n], 0, 0, 0);
    }

    // epilogue: C/D layout col = lane&15, row = (lane>>4)*4 + j
#pragma unroll
    for (int m = 0; m < 2; m++) {
#pragma unroll
        for (int j = 0; j < 4; j++) {
            const int grow = row0 + wr * 32 + m * 16 + h * 4 + j;
            int i1 = 0, i2 = 0;
            if constexpr (EPI == 3) { i1 = idx1[grow]; i2 = idx2[grow]; }
#pragma unroll
            for (int n = 0; n < 4; n++) {
                const int gcol = col0 + wc * 64 + n * 16 + fr;
                if (EPI == 4 && gcol >= Nd) continue;
                float v = acc[m][n][j] +
                          (gcol < 256 ? bias[gcol] : bias2[gcol - 256]);
                if constexpr (EPI == 1) v = fmaxf(v, 0.f);
                if constexpr (EPI == 2)
                    v += b2f(resid[(size_t)grow * Nd + gcol]);
                if constexpr (EPI == 3) {
                    v += b2f(resid[(size_t)grow * Nd + gcol]);
                    v += gcn[(size_t)grow * Nd + gcol];
                    v += emb1[(size_t)i1 * Nd + gcol];
                    v += emb2[(size_t)i2 * Nd + gcol];
                }
                if constexpr (EPI == 4)
                    ((float*)Cv)[(size_t)grow * Nd + gcol] = v;
                else
                    ((u16*)Cv)[(size_t)grow * Nd + gcol] = f2b(v);
            }
        }
    }
}

__device__ inline float bfly_sum(float v) {
#pragma unroll
    for (int off = 32; off; off >>= 1) v += __shfl_xor(v, off, 64);
    return v;  // all lanes
}

// ---------------------------------------------------------------------------
// Stage 1: one hyperedge per wave (4/block). KVn = [N][512] (k|v fused).
// ---------------------------------------------------------------------------
__global__ __launch_bounds__(256) void edge_attn(
    const u16* __restrict__ KVn, const u16* __restrict__ QE,
    const float* __restrict__ efeat,
    const int* __restrict__ e2n, const float* __restrict__ cent1,
    const float* __restrict__ g, const float* __restrict__ bb,
    u16* __restrict__ XE)
{
    const int lane = threadIdx.x & 63, w = threadIdx.x >> 6;
    const int e = blockIdx.x * 4 + w;
    const int c4 = lane * 4;

    ushort4 q4 = *(const ushort4*)&QE[(size_t)e * QDIM + c4];
    const float q0 = b2f(q4.x), q1 = b2f(q4.y), q2 = b2f(q4.z), q3 = b2f(q4.w);

    int rows[DE]; float sc[DE];
#pragma unroll
    for (int d = 0; d < DE; d++) rows[d] = e2n[(size_t)e * DE + d];
#pragma unroll
    for (int d = 0; d < DE; d++) {
        ushort4 k4 = *(const ushort4*)&KVn[(size_t)rows[d] * 512 + c4];
        float p = q0 * b2f(k4.x) + q1 * b2f(k4.y) + q2 * b2f(k4.z) + q3 * b2f(k4.w);
        p = bfly_sum(p);
        sc[d] = (p > 0.f ? p : 0.01f * p) * ATT_SCALE + cent1[(size_t)e * DE + d];
    }
    float mx = sc[0];
#pragma unroll
    for (int d = 1; d < DE; d++) mx = fmaxf(mx, sc[d]);
    float s = 0.f;
#pragma unroll
    for (int d = 0; d < DE; d++) { sc[d] = __expf(sc[d] - mx); s += sc[d]; }
    const float inv = 1.f / s;

    float a0 = 0.f, a1 = 0.f, a2 = 0.f, a3 = 0.f;
#pragma unroll
    for (int d = 0; d < DE; d++) {
        ushort4 v4 = *(const ushort4*)&KVn[(size_t)rows[d] * 512 + 256 + c4];
        float sd = sc[d] * inv;
        a0 = fmaf(sd, b2f(v4.x), a0); a1 = fmaf(sd, b2f(v4.y), a1);
        a2 = fmaf(sd, b2f(v4.z), a2); a3 = fmaf(sd, b2f(v4.w), a3);
    }
    float4 ef = *(const float4*)&efeat[(size_t)e * DIM + c4];
    float x0 = a0 + ef.x, x1 = a1 + ef.y, x2 = a2 + ef.z, x3 = a3 + ef.w;

    float mu = bfly_sum(x0 + x1 + x2 + x3) * (1.f / DIM);
    float d0 = x0 - mu, d1 = x1 - mu, d2 = x2 - mu, d3 = x3 - mu;
    float var = bfly_sum(d0 * d0 + d1 * d1 + d2 * d2 + d3 * d3) * (1.f / DIM);
    float r = rsqrtf(var + LN_EPS);
    float4 gv = *(const float4*)&g[c4];
    float4 bv = *(const float4*)&bb[c4];
    ushort4 o;
    o.x = f2b(d0 * r * gv.x + bv.x); o.y = f2b(d1 * r * gv.y + bv.y);
    o.z = f2b(d2 * r * gv.z + bv.z); o.w = f2b(d3 * r * gv.w + bv.w);
    *(ushort4*)&XE[(size_t)e * DIM + c4] = o;
}

// ---------------------------------------------------------------------------
// Stage 2: one node per wave (4/block). KVe = [E][512] (k|v fused).
// ---------------------------------------------------------------------------
__global__ __launch_bounds__(256) void node_attn(
    const u16* __restrict__ KVe, const u16* __restrict__ QV,
    const u16* __restrict__ FV,
    const int* __restrict__ n2e, const float* __restrict__ cent2,
    const float* __restrict__ g, const float* __restrict__ bb,
    u16* __restrict__ XV)
{
    const int lane = threadIdx.x & 63, w = threadIdx.x >> 6;
    const int n = blockIdx.x * 4 + w;
    const int c4 = lane * 4;

    ushort4 q4 = *(const ushort4*)&QV[(size_t)n * QDIM + c4];
    const float q0 = b2f(q4.x), q1 = b2f(q4.y), q2 = b2f(q4.z), q3 = b2f(q4.w);

    int rows[DV]; float sc[DV];
#pragma unroll
    for (int d = 0; d < DV; d++) rows[d] = n2e[(size_t)n * DV + d];
#pragma unroll
    for (int d = 0; d < DV; d++) {
        ushort4 k4 = *(const ushort4*)&KVe[(size_t)rows[d] * 512 + c4];
        float p = q0 * b2f(k4.x) + q1 * b2f(k4.y) + q2 * b2f(k4.z) + q3 * b2f(k4.w);
        p = bfly_sum(p);
        sc[d] = (p > 0.f ? p : 0.01f * p) * ATT_SCALE + cent2[(size_t)n * DV + d];
    }
    float mx = sc[0];
#pragma unroll
    for (int d = 1; d < DV; d++) mx = fmaxf(mx, sc[d]);
    float s = 0.f;
#pragma unroll
    for (int d = 0; d < DV; d++) { sc[d] = __expf(sc[d] - mx); s += sc[d]; }
    const float inv = 1.f / s;

    float a0 = 0.f, a1 = 0.f, a2 = 0.f, a3 = 0.f;
#pragma unroll
    for (int d = 0; d < DV; d++) {
        ushort4 v4 = *(const ushort4*)&KVe[(size_t)rows[d] * 512 + 256 + c4];
        float sd = sc[d] * inv;
        a0 = fmaf(sd, b2f(v4.x), a0); a1 = fmaf(sd, b2f(v4.y), a1);
        a2 = fmaf(sd, b2f(v4.z), a2); a3 = fmaf(sd, b2f(v4.w), a3);
    }
    ushort4 f4 = *(const ushort4*)&FV[(size_t)n * DIM + c4];
    float x0 = a0 + b2f(f4.x), x1 = a1 + b2f(f4.y);
    float x2 = a2 + b2f(f4.z), x3 = a3 + b2f(f4.w);

    float mu = bfly_sum(x0 + x1 + x2 + x3) * (1.f / DIM);
    float d0 = x0 - mu, d1 = x1 - mu, d2 = x2 - mu, d3 = x3 - mu;
    float var = bfly_sum(d0 * d0 + d1 * d1 + d2 * d2 + d3 * d3) * (1.f / DIM);
    float r = rsqrtf(var + LN_EPS);
    float4 gv = *(const float4*)&g[c4];
    float4 bv = *(const float4*)&bb[c4];
    ushort4 o;
    o.x = f2b(d0 * r * gv.x + bv.x); o.y = f2b(d1 * r * gv.y + bv.y);
    o.z = f2b(d2 * r * gv.z + bv.z); o.w = f2b(d3 * r * gv.w + bv.w);
    *(ushort4*)&XV[(size_t)n * DIM + c4] = o;
}

// Row LayerNorm, bf16, one row per wave (4/block), in-place safe
__global__ __launch_bounds__(256) void ln_rows(
    const u16* __restrict__ X, const float* __restrict__ g,
    const float* __restrict__ bb, u16* __restrict__ Y)
{
    const int lane = threadIdx.x & 63, w = threadIdx.x >> 6;
    const int row = blockIdx.x * 4 + w;
    const int c4 = lane * 4;
    ushort4 v4 = *(const ushort4*)&X[(size_t)row * DIM + c4];
    float x0 = b2f(v4.x), x1 = b2f(v4.y), x2 = b2f(v4.z), x3 = b2f(v4.w);
    float mu = bfly_sum(x0 + x1 + x2 + x3) * (1.f / DIM);
    float d0 = x0 - mu, d1 = x1 - mu, d2 = x2 - mu, d3 = x3 - mu;
    float var = bfly_sum(d0 * d0 + d1 * d1 + d2 * d2 + d3 * d3) * (1.f / DIM);
    float r = rsqrtf(var + LN_EPS);
    float4 gv = *(const float4*)&g[c4];
    float4 bv = *(const float4*)&bb[c4];
    ushort4 o;
    o.x = f2b(d0 * r * gv.x + bv.x); o.y = f2b(d1 * r * gv.y + bv.y);
    o.z = f2b(d2 * r * gv.z + bv.z); o.w = f2b(d3 * r * gv.w + bv.w);
    *(ushort4*)&Y[(size_t)row * DIM + c4] = o;
}

extern "C" void kernel_launch(void* const* d_in, const int* in_sizes, int n_in,
                              void* d_out, int out_size, void* d_ws, size_t ws_size,
                              hipStream_t stream)
{
    const float* vfeat  = (const float*)d_in[0];
    const float* efeat  = (const float*)d_in[1];
    const float* eign   = (const float*)d_in[2];
    const float* gcn    = (const float*)d_in[3];
    const float* cent1  = (const float*)d_in[4];
    const float* cent2  = (const float*)d_in[5];
    const int*   cidx   = (const int*)d_in[6];
    const int*   uidx   = (const int*)d_in[7];
    const int*   e2n    = (const int*)d_in[8];
    const int*   n2e    = (const int*)d_in[9];
    const float* W_vtx  = (const float*)d_in[10]; const float* b_vtx = (const float*)d_in[11];
    const float* W_pe   = (const float*)d_in[12]; const float* b_pe  = (const float*)d_in[13];
    const float* cs_emb = (const float*)d_in[14]; const float* un_emb= (const float*)d_in[15];
    const float* W_kv   = (const float*)d_in[16]; const float* b_kv  = (const float*)d_in[17];
    const float* W_vv   = (const float*)d_in[18]; const float* b_vv  = (const float*)d_in[19];
    const float* W_qe   = (const float*)d_in[20]; const float* b_qe  = (const float*)d_in[21];
    const float* W_ke   = (const float*)d_in[22]; const float* b_ke  = (const float*)d_in[23];
    const float* W_ve   = (const float*)d_in[24]; const float* b_ve  = (const float*)d_in[25];
    const float* W_qv   = (const float*)d_in[26]; const float* b_qv  = (const float*)d_in[27];
    const float* W_l1   = (const float*)d_in[28]; const float* b_l1  = (const float*)d_in[29];
    const float* W_l2   = (const float*)d_in[30]; const float* b_l2  = (const float*)d_in[31];
    const float* W_l3   = (const float*)d_in[32]; const float* b_l3  = (const float*)d_in[33];
    const float* W_l4   = (const float*)d_in[34]; const float* b_l4  = (const float*)d_in[35];
    const float* ln1_g  = (const float*)d_in[36]; const float* ln1_b = (const float*)d_in[37];
    const float* ln2_g  = (const float*)d_in[38]; const float* ln2_b = (const float*)d_in[39];
    const float* W_cls  = (const float*)d_in[40]; const float* b_cls = (const float*)d_in[41];
    float* out = (float*)d_out;

    const size_t NE = (size_t)N_NODES * DIM;   // 10,240,000
    const size_t EE = (size_t)N_EDGES * DIM;   //  2,048,000
    u16* ws = (u16*)d_ws;
    u16* FV  = ws;             // assembled feat_v
    u16* T0  = FV + NE;        // lin1 -> QV -> l3-out
    u16* B2  = T0 + NE;        // x_v
    u16* KVn = B2 + NE;        // [N][512] k_n|v_n
    u16* Vb  = KVn + 2 * NE;   // bf16 vfeat
    u16* Gb  = Vb + NE;        // bf16 eign
    u16* Eb  = Gb + (size_t)N_NODES * EIGD;    // bf16 efeat
    u16* QEb = Eb + EE;
    u16* XE  = QEb + EE;
    u16* TE  = XE + EE;
    u16* FE  = TE + EE;
    u16* KVe = FE + EE;        // [E][512] k_e|v_e
    u16* Wp  = KVe + 2 * EE;   // 13 * 65536
    u16* Wt_vtx = Wp +  0*65536; u16* Wt_pe = Wp +  1*65536;
    u16* Wt_kv  = Wp +  2*65536;  /* vv at 3 (adjacent) */
    u16* Wt_qe  = Wp +  4*65536; u16* Wt_ke = Wp +  5*65536;
    /* ve at 6 (adjacent) */     u16* Wt_qv = Wp +  7*65536;
    u16* Wt_l1  = Wp +  8*65536; u16* Wt_l2 = Wp +  9*65536;
    u16* Wt_l3  = Wp + 10*65536; u16* Wt_l4 = Wp + 11*65536;
    u16* Wt_cls = Wp + 12*65536;

    const dim3 blk(256);
    const dim3 gW(8, 8, 13);
    const dim3 gN1(2, N_NODES / 64);   // Nd=256, N-side: (2,625)
    const dim3 gN2(4, N_NODES / 64);   // Nd=512
    const dim3 gE1(2, N_EDGES / 64);   // Nd=256, E-side: (2,125)
    const dim3 gE2(4, N_EDGES / 64);   // Nd=512
    const dim3 gCl(1, N_NODES / 64);   // Nd=40

    // ---- prep: weight transpose-cast + activation casts ----
    prep_weights<<<gW, blk, 0, stream>>>(
        W_vtx, W_pe, W_kv, W_vv, W_qe, W_ke, W_ve, W_qv,
        W_l1, W_l2, W_l3, W_l4, W_cls, Wp);
    cast_bf16<<<2048, blk, 0, stream>>>(vfeat, Vb, (int)(NE / 4));
    cast_bf16<<<1024, blk, 0, stream>>>(eign, Gb, N_NODES * EIGD / 4);
    cast_bf16<<<1024, blk, 0, stream>>>(efeat, Eb, (int)(EE / 4));

    // ---- feature assembly ----
    gemm_mfma<0><<<gN1, blk, 0, stream>>>(Vb, Wt_vtx, b_vtx, b_vtx, nullptr,
        nullptr, nullptr, nullptr, nullptr, nullptr, T0, N_NODES, DIM, DIM);
    gemm_mfma<3><<<gN1, blk, 0, stream>>>(Gb, Wt_pe, b_pe, b_pe, T0,
        gcn, cs_emb, un_emb, cidx, uidx, FV, N_NODES, EIGD, DIM);

    // ---- stage 1 ----
    gemm_mfma<0><<<gN2, blk, 0, stream>>>(FV, Wt_kv, b_kv, b_vv, nullptr,
        nullptr, nullptr, nullptr, nullptr, nullptr, KVn, N_NODES, DIM, 512);   // k_n|v_n
    gemm_mfma<0><<<gE1, blk, 0, stream>>>(Eb, Wt_qe, b_qe, b_qe, nullptr,
        nullptr, nullptr, nullptr, nullptr, nullptr, QEb, N_EDGES, DIM, QDIM);  // q_e
    edge_attn<<<N_EDGES / 4, blk, 0, stream>>>(KVn, QEb, efeat, e2n, cent1,
        ln1_g, ln1_b, XE);
    gemm_mfma<1><<<gE1, blk, 0, stream>>>(XE, Wt_l1, b_l1, b_l1, nullptr,
        nullptr, nullptr, nullptr, nullptr, nullptr, TE, N_EDGES, DIM, QDIM);   // relu(l1)
    gemm_mfma<2><<<gE1, blk, 0, stream>>>(TE, Wt_l2, b_l2, b_l2, XE,
        nullptr, nullptr, nullptr, nullptr, nullptr, FE, N_EDGES, QDIM, DIM);   // + x_e
    ln_rows<<<N_EDGES / 4, blk, 0, stream>>>(FE, ln1_g, ln1_b, FE);             // feat_e

    // ---- stage 2 ----
    gemm_mfma<0><<<gE2, blk, 0, stream>>>(FE, Wt_ke, b_ke, b_ve, nullptr,
        nullptr, nullptr, nullptr, nullptr, nullptr, KVe, N_EDGES, DIM, 512);   // k_e|v_e
    gemm_mfma<0><<<gN1, blk, 0, stream>>>(FV, Wt_qv, b_qv, b_qv, nullptr,
        nullptr, nullptr, nullptr, nullptr, nullptr, T0, N_NODES, DIM, QDIM);   // q_v
    node_attn<<<N_NODES / 4, blk, 0, stream>>>(KVe, T0, FV, n2e, cent2,
        ln2_g, ln2_b, B2);                                                      // x_v
    gemm_mfma<1><<<gN1, blk, 0, stream>>>(B2, Wt_l3, b_l3, b_l3, nullptr,
        nullptr, nullptr, nullptr, nullptr, nullptr, T0, N_NODES, DIM, QDIM);   // relu(l3)
    gemm_mfma<2><<<gN1, blk, 0, stream>>>(T0, Wt_l4, b_l4, b_l4, B2,
        nullptr, nullptr, nullptr, nullptr, nullptr, FV, N_NODES, QDIM, DIM);   // + x_v
    ln_rows<<<N_NODES / 4, blk, 0, stream>>>(FV, ln2_g, ln2_b, FV);             // feat_v

    // ---- classifier ----
    gemm_mfma<4><<<gCl, blk, 0, stream>>>(FV, Wt_cls, b_cls, b_cls, nullptr,
        nullptr, nullptr, nullptr, nullptr, nullptr, out, N_NODES, DIM, NCLS);
}

// Round 4
// 264.280 us; speedup vs baseline: 3.5877x; 1.0190x over previous
//
// R3: dual-source assembly GEMM, Nd=768 KVQ mega-GEMM, LN-fused l2/l4 GEMMs,
// single-pass online-softmax edge_attn, full-register node_attn, merged casts.
#include <hip/hip_runtime.h>
#include <hip/hip_bf16.h>
#include <cstddef>

#define N_NODES 40000
#define N_EDGES 8000
#define DE 32
#define DV 8
#define DIM 256
#define QDIM 256
#define EIGD 64
#define NCLS 40
#define LN_EPS 1e-5f
#define ATT_SCALE 0.0625f   // 1/sqrt(256)

typedef unsigned short u16;
typedef unsigned int u32;
using i16x8 = __attribute__((ext_vector_type(8))) short;
using f32x4 = __attribute__((ext_vector_type(4))) float;

__device__ inline u16 f2b(float f) {   // RNE f32 -> bf16 bits
    union { float f; u32 u; } c; c.f = f;
    u32 u = c.u + 0x7FFF + ((c.u >> 16) & 1);
    return (u16)(u >> 16);
}
__device__ inline float b2f(u16 b) {
    union { u32 u; float f; } c; c.u = (u32)b << 16;
    return c.f;
}

__device__ inline void gload_lds16(const u16* g, u16* l) {
    __builtin_amdgcn_global_load_lds(
        (const __attribute__((address_space(1))) void*)g,
        (__attribute__((address_space(3))) void*)l, 16, 0, 0);
}

#define VMCNT10 asm volatile("s_waitcnt vmcnt(10)" ::: "memory")
#define VMCNT6  asm volatile("s_waitcnt vmcnt(6)" ::: "memory")
#define VMCNT0  asm volatile("s_waitcnt vmcnt(0)" ::: "memory")
#define LGKM0   asm volatile("s_waitcnt lgkmcnt(0)" ::: "memory")

// ---------------------------------------------------------------------------
// One cast kernel for vfeat, eign, efeat -> bf16
// ---------------------------------------------------------------------------
__global__ __launch_bounds__(256) void cast_all(
    const float* __restrict__ vfeat, const float* __restrict__ eign,
    const float* __restrict__ efeat,
    u16* __restrict__ Vb, u16* __restrict__ Gb, u16* __restrict__ Eb)
{
    const int A4 = N_NODES * DIM / 4;          // 2,560,000
    const int B4 = N_NODES * EIGD / 4;         //   640,000
    const int C4 = N_EDGES * DIM / 4;          //   512,000
    const int tot = A4 + B4 + C4;
    for (int i = blockIdx.x * 256 + threadIdx.x; i < tot; i += gridDim.x * 256) {
        const float4* s; ushort4* d; int j;
        if (i < A4)            { s = (const float4*)vfeat; d = (ushort4*)Vb; j = i; }
        else if (i < A4 + B4)  { s = (const float4*)eign;  d = (ushort4*)Gb; j = i - A4; }
        else                   { s = (const float4*)efeat; d = (ushort4*)Eb; j = i - A4 - B4; }
        float4 v = s[j];
        ushort4 o;
        o.x = f2b(v.x); o.y = f2b(v.y); o.z = f2b(v.z); o.w = f2b(v.w);
        d[j] = o;
    }
}

// ---------------------------------------------------------------------------
// Batched transpose-cast. Slot order (so fused B matrices are contiguous):
// 0 vtx, 1 pe, 2 kv, 3 vv, 4 qv, 5 qe, 6 ke, 7 ve, 8 l1, 9 l2, 10 l3,
// 11 l4, 12 cls.  [kv|vv|qv] = rows 0..767 of a [768][256]; [ke|ve] = [512][256].
// ---------------------------------------------------------------------------
__global__ __launch_bounds__(256) void prep_weights(
    const float* w0, const float* w1, const float* w2, const float* w3,
    const float* w4, const float* w5, const float* w6, const float* w7,
    const float* w8, const float* w9, const float* w10, const float* w11,
    const float* w12, u16* __restrict__ pool)
{
    const float* srcs[13] = {w0,w1,w2,w3,w4,w5,w6,w7,w8,w9,w10,w11,w12};
    const int Ks[13]  = {256,64,256,256,256,256,256,256,256,256,256,256,256};
    const int Nds[13] = {256,256,256,256,256,256,256,256,256,256,256,256,40};
    const int id = blockIdx.z;
    const float* W = srcs[id];
    u16* Wt = pool + (size_t)id * 65536;
    const int K = Ks[id], Nd = Nds[id];
    const int k0 = blockIdx.x * 32, n0 = blockIdx.y * 32;
    if (k0 >= K || n0 >= Nd) return;

    __shared__ float tile[32][33];
    const int x = threadIdx.x & 31, y4 = (threadIdx.x >> 5) * 4;
#pragma unroll
    for (int j = 0; j < 4; j++) {
        int k = k0 + y4 + j;
        tile[y4 + j][x] = (k < K && (n0 + x) < Nd) ? W[(size_t)k * Nd + n0 + x] : 0.f;
    }
    __syncthreads();
#pragma unroll
    for (int j = 0; j < 4; j++) {
        int n = n0 + y4 + j;
        if (n < Nd && (k0 + x) < K)
            Wt[(size_t)n * K + k0 + x] = f2b(tile[x][y4 + j]);
    }
}

// ---------------------------------------------------------------------------
// Pipelined bf16 MFMA GEMM (BM=64, BN=128, BK=64, 4 waves 2x2).
// Optional dual source: A1[M][K1] then A2[M][64] (B side: Wt then Wt2[*][64]).
// Bias segments of 256 cols: bias0/bias1/bias2 by gcol>>8.
// EPI: 0 ->bf16; 1 relu->bf16; 3 bias0+bias1+gcn+emb1[i1]+emb2[i2]->bf16;
//      4 ->f32 with col guard.
// ---------------------------------------------------------------------------
template <int EPI, bool DUAL>
__global__ __launch_bounds__(256) void gemm_mfma(
    const u16* __restrict__ A, const u16* __restrict__ A2,
    const u16* __restrict__ Wt, const u16* __restrict__ Wt2,
    const float* __restrict__ bias0, const float* __restrict__ bias1,
    const float* __restrict__ bias2,
    const float* __restrict__ gcn, const float* __restrict__ emb1,
    const float* __restrict__ emb2, const int* __restrict__ idx1,
    const int* __restrict__ idx2,
    void* __restrict__ Cv, int M, int K1, int Ktot, int Nd)
{
    __shared__ u16 Asm[2][64 * 64];
    __shared__ u16 Bsm[2][128 * 64];
    const int t = threadIdx.x;
    const int lane = t & 63, w = t >> 6;
    const int wr = w >> 1, wc = w & 1;
    const int row0 = blockIdx.y * 64, col0 = blockIdx.x * 128;

    f32x4 acc[2][4] = {};

    const int srow = lane >> 3;
    const int sblk = ((lane & 7) ^ srow) * 8;   // inverse-swizzled source blk

    const int fr = lane & 15, h = lane >> 4;
    const int lsw = fr & 7;
    const int nt = Ktot >> 6;

    auto stage = [&](int buf, int kt) {
        const int k0 = kt << 6;
        const bool first = !DUAL || (k0 < K1);
#pragma unroll
        for (int i = 0; i < 2; i++) {           // A rows w*16+i*8 (+srow)
            int r = w * 16 + i * 8;
            const u16* gp = first
                ? A  + (size_t)(row0 + r + srow) * K1 + k0 + sblk
                : A2 + (size_t)(row0 + r + srow) * 64 + (k0 - K1) + sblk;
            gload_lds16(gp, &Asm[buf][r * 64]);
        }
#pragma unroll
        for (int i = 0; i < 4; i++) {           // B rows w*32+i*8 (+srow)
            int r = w * 32 + i * 8;
            int ng = col0 + r + srow; if (ng > Nd - 1) ng = Nd - 1;
            const u16* gp = first
                ? Wt  + (size_t)ng * K1 + k0 + sblk
                : Wt2 + (size_t)ng * 64 + (k0 - K1) + sblk;
            gload_lds16(gp, &Bsm[buf][r * 64]);
        }
    };

    stage(0, 0);
    for (int kt = 0; kt < nt; ++kt) {
        const int cur = kt & 1;
        const bool more = (kt + 1 < nt);
        if (more) stage(cur ^ 1, kt + 1);
        if (more) { VMCNT6; } else { VMCNT0; }
        __builtin_amdgcn_s_barrier();           // buf[cur] staged

        i16x8 af[2][2], bf[2][4];
#pragma unroll
        for (int kk = 0; kk < 2; kk++) {
#pragma unroll
            for (int m = 0; m < 2; m++)
                af[kk][m] = *(const i16x8*)&Asm[cur][(wr * 32 + m * 16 + fr) * 64 +
                                                    ((kk * 4 + h) ^ lsw) * 8];
#pragma unroll
            for (int n = 0; n < 4; n++)
                bf[kk][n] = *(const i16x8*)&Bsm[cur][(wc * 64 + n * 16 + fr) * 64 +
                                                    ((kk * 4 + h) ^ lsw) * 8];
        }
        LGKM0;
        __builtin_amdgcn_sched_barrier(0);
        __builtin_amdgcn_s_barrier();           // reads done

#pragma unroll
        for (int kk = 0; kk < 2; kk++)
#pragma unroll
            for (int m = 0; m < 2; m++)
#pragma unroll
                for (int n = 0; n < 4; n++)
                    acc[m][n] = __builtin_amdgcn_mfma_f32_16x16x32_bf16(
                        af[kk][m], bf[kk][n], acc[m][n], 0, 0, 0);
    }

#pragma unroll
    for (int m = 0; m < 2; m++) {
#pragma unroll
        for (int j = 0; j < 4; j++) {
            const int grow = row0 + wr * 32 + m * 16 + h * 4 + j;
            int i1 = 0, i2 = 0;
            if constexpr (EPI == 3) { i1 = idx1[grow]; i2 = idx2[grow]; }
#pragma unroll
            for (int n = 0; n < 4; n++) {
                const int gcol = col0 + wc * 64 + n * 16 + fr;
                if (EPI == 4 && gcol >= Nd) continue;
                float v;
                if constexpr (EPI == 3) {
                    v = acc[m][n][j] + bias0[gcol] + bias1[gcol];
                    v += gcn[(size_t)grow * Nd + gcol];
                    v += emb1[(size_t)i1 * Nd + gcol];
                    v += emb2[(size_t)i2 * Nd + gcol];
                } else {
                    const float* bp = (gcol < 256) ? bias0
                                     : ((gcol < 512) ? bias1 : bias2);
                    v = acc[m][n][j] + bp[gcol & 255];
                }
                if constexpr (EPI == 1) v = fmaxf(v, 0.f);
                if constexpr (EPI == 4)
                    ((float*)Cv)[(size_t)grow * Nd + gcol] = v;
                else
                    ((u16*)Cv)[(size_t)grow * Nd + gcol] = f2b(v);
            }
        }
    }
}

// ---------------------------------------------------------------------------
// LN-fused GEMM: Y = LN(A@Wt^T + bias + resid). BM=64, BN=Nd=256, BK=64,
// 4 waves, wave w owns cols w*64 (all 64 rows). Cross-wave LN via LDS
// sum/sumsq (var = E[x^2]-mu^2).
// ---------------------------------------------------------------------------
__global__ __launch_bounds__(256) void gemm_ln(
    const u16* __restrict__ A, const u16* __restrict__ Wt,
    const float* __restrict__ bias, const u16* __restrict__ resid,
    const float* __restrict__ g, const float* __restrict__ bb,
    u16* __restrict__ Y, int M)
{
    __shared__ u16 Asm[2][64 * 64];     // 16 KB (aliased by LN reductions)
    __shared__ u16 Bsm[2][256 * 64];    // 64 KB
    const int t = threadIdx.x;
    const int lane = t & 63, w = t >> 6;
    const int row0 = blockIdx.y * 64;

    f32x4 acc[4][4] = {};

    const int srow = lane >> 3;
    const int sblk = ((lane & 7) ^ srow) * 8;
    const int fr = lane & 15, h = lane >> 4;
    const int lsw = fr & 7;

    auto stage = [&](int buf, int kt) {
        const int k0 = kt << 6;
#pragma unroll
        for (int i = 0; i < 2; i++) {
            int r = w * 16 + i * 8;
            gload_lds16(A + (size_t)(row0 + r + srow) * 256 + k0 + sblk,
                        &Asm[buf][r * 64]);
        }
#pragma unroll
        for (int i = 0; i < 8; i++) {
            int r = w * 64 + i * 8;
            gload_lds16(Wt + (size_t)(r + srow) * 256 + k0 + sblk,
                        &Bsm[buf][r * 64]);
        }
    };

    stage(0, 0);
    for (int kt = 0; kt < 4; ++kt) {
        const int cur = kt & 1;
        const bool more = (kt < 3);
        if (more) stage(cur ^ 1, kt + 1);
        if (more) { VMCNT10; } else { VMCNT0; }
        __builtin_amdgcn_s_barrier();

        i16x8 af[2][4], bf[2][4];
#pragma unroll
        for (int kk = 0; kk < 2; kk++) {
#pragma unroll
            for (int m = 0; m < 4; m++)
                af[kk][m] = *(const i16x8*)&Asm[cur][(m * 16 + fr) * 64 +
                                                    ((kk * 4 + h) ^ lsw) * 8];
#pragma unroll
            for (int n = 0; n < 4; n++)
                bf[kk][n] = *(const i16x8*)&Bsm[cur][(w * 64 + n * 16 + fr) * 64 +
                                                    ((kk * 4 + h) ^ lsw) * 8];
        }
        LGKM0;
        __builtin_amdgcn_sched_barrier(0);
        __builtin_amdgcn_s_barrier();

#pragma unroll
        for (int kk = 0; kk < 2; kk++)
#pragma unroll
            for (int m = 0; m < 4; m++)
#pragma unroll
                for (int n = 0; n < 4; n++)
                    acc[m][n] = __builtin_amdgcn_mfma_f32_16x16x32_bf16(
                        af[kk][m], bf[kk][n], acc[m][n], 0, 0, 0);
    }

    // epilogue: v = acc + bias + resid; then row LN across 4 waves
    float* redS = (float*)&Asm[0][0];          // [64][4]
    float* redQ = redS + 256;                  // [64][4]
#pragma unroll
    for (int m = 0; m < 4; m++) {
#pragma unroll
        for (int j = 0; j < 4; j++) {
            const int grow = row0 + m * 16 + h * 4 + j;
            float s = 0.f, q = 0.f;
#pragma unroll
            for (int n = 0; n < 4; n++) {
                const int gcol = w * 64 + n * 16 + fr;
                float v = acc[m][n][j] + bias[gcol] +
                          b2f(resid[(size_t)grow * 256 + gcol]);
                acc[m][n][j] = v;
                s += v; q += v * v;
            }
#pragma unroll
            for (int off = 1; off < 16; off <<= 1) {
                s += __shfl_xor(s, off, 64);
                q += __shfl_xor(q, off, 64);
            }
            if (fr == 0) {
                redS[(m * 16 + h * 4 + j) * 4 + w] = s;
                redQ[(m * 16 + h * 4 + j) * 4 + w] = q;
            }
        }
    }
    __syncthreads();
#pragma unroll
    for (int m = 0; m < 4; m++) {
#pragma unroll
        for (int j = 0; j < 4; j++) {
            const int r = m * 16 + h * 4 + j;
            const int grow = row0 + r;
            float4 s4 = *(const float4*)&redS[r * 4];
            float4 q4 = *(const float4*)&redQ[r * 4];
            float mu = (s4.x + s4.y + s4.z + s4.w) * (1.f / DIM);
            float var = (q4.x + q4.y + q4.z + q4.w) * (1.f / DIM) - mu * mu;
            float rr = rsqrtf(var + LN_EPS);
#pragma unroll
            for (int n = 0; n < 4; n++) {
                const int gcol = w * 64 + n * 16 + fr;
                float y = (acc[m][n][j] - mu) * rr * g[gcol] + bb[gcol];
                Y[(size_t)grow * 256 + gcol] = f2b(y);
            }
        }
    }
}

// ---------------------------------------------------------------------------
// Stage 1: one edge per wave, single-pass gather with exact online softmax.
// KVQn = [N][768] (k|v|q fused); K at +0, V at +256.
// ---------------------------------------------------------------------------
__global__ __launch_bounds__(256) void edge_attn(
    const u16* __restrict__ KVQn, const u16* __restrict__ QE,
    const float* __restrict__ efeat,
    const int* __restrict__ e2n, const float* __restrict__ cent1,
    const float* __restrict__ g, const float* __restrict__ bb,
    u16* __restrict__ XE)
{
    const int lane = threadIdx.x & 63, w = threadIdx.x >> 6;
    const int e = blockIdx.x * 4 + w;
    const int c4 = lane * 4;

    ushort4 q4 = *(const ushort4*)&QE[(size_t)e * QDIM + c4];
    const float q0 = b2f(q4.x), q1 = b2f(q4.y), q2 = b2f(q4.z), q3 = b2f(q4.w);

    int rows[DE];
#pragma unroll
    for (int d = 0; d < DE; d++) rows[d] = e2n[(size_t)e * DE + d];

    float m = -1e30f, l = 0.f;
    float a0 = 0.f, a1 = 0.f, a2 = 0.f, a3 = 0.f;
#pragma unroll
    for (int d0 = 0; d0 < DE; d0 += 4) {
        ushort4 k4[4], v4[4]; float p[4];
#pragma unroll
        for (int j = 0; j < 4; j++) {
            const u16* base = KVQn + (size_t)rows[d0 + j] * 768 + c4;
            k4[j] = *(const ushort4*)base;
            v4[j] = *(const ushort4*)(base + 256);
        }
#pragma unroll
        for (int j = 0; j < 4; j++)
            p[j] = q0 * b2f(k4[j].x) + q1 * b2f(k4[j].y)
                 + q2 * b2f(k4[j].z) + q3 * b2f(k4[j].w);
#pragma unroll
        for (int off = 32; off; off >>= 1)
#pragma unroll
            for (int j = 0; j < 4; j++) p[j] += __shfl_xor(p[j], off, 64);
#pragma unroll
        for (int j = 0; j < 4; j++) {
            float s = p[j];
            s = (s > 0.f ? s : 0.01f * s) * ATT_SCALE + cent1[(size_t)e * DE + d0 + j];
            float wgt;
            if (s > m) {            // wave-uniform branch
                float f = __expf(m - s);
                a0 *= f; a1 *= f; a2 *= f; a3 *= f; l *= f;
                m = s; wgt = 1.f;
            } else {
                wgt = __expf(s - m);
            }
            l += wgt;
            a0 = fmaf(wgt, b2f(v4[j].x), a0);
            a1 = fmaf(wgt, b2f(v4[j].y), a1);
            a2 = fmaf(wgt, b2f(v4[j].z), a2);
            a3 = fmaf(wgt, b2f(v4[j].w), a3);
        }
    }
    const float inv = 1.f / l;
    float4 ef = *(const float4*)&efeat[(size_t)e * DIM + c4];
    float x0 = a0 * inv + ef.x, x1 = a1 * inv + ef.y;
    float x2 = a2 * inv + ef.z, x3 = a3 * inv + ef.w;

    float mu = x0 + x1 + x2 + x3;
#pragma unroll
    for (int off = 32; off; off >>= 1) mu += __shfl_xor(mu, off, 64);
    mu *= (1.f / DIM);
    float d0_ = x0 - mu, d1 = x1 - mu, d2 = x2 - mu, d3 = x3 - mu;
    float var = d0_ * d0_ + d1 * d1 + d2 * d2 + d3 * d3;
#pragma unroll
    for (int off = 32; off; off >>= 1) var += __shfl_xor(var, off, 64);
    var *= (1.f / DIM);
    float r = rsqrtf(var + LN_EPS);
    float4 gv = *(const float4*)&g[c4];
    float4 bv = *(const float4*)&bb[c4];
    ushort4 o;
    o.x = f2b(d0_ * r * gv.x + bv.x); o.y = f2b(d1 * r * gv.y + bv.y);
    o.z = f2b(d2 * r * gv.z + bv.z); o.w = f2b(d3 * r * gv.w + bv.w);
    *(ushort4*)&XE[(size_t)e * DIM + c4] = o;
}

// ---------------------------------------------------------------------------
// Stage 2: one node per wave, all 8 K+V rows in registers, exact softmax.
// KVe = [E][512]; q_v read from KVQn[n][512..767].
// ---------------------------------------------------------------------------
__global__ __launch_bounds__(256) void node_attn(
    const u16* __restrict__ KVe, const u16* __restrict__ KVQn,
    const u16* __restrict__ FV,
    const int* __restrict__ n2e, const float* __restrict__ cent2,
    const float* __restrict__ g, const float* __restrict__ bb,
    u16* __restrict__ XV)
{
    const int lane = threadIdx.x & 63, w = threadIdx.x >> 6;
    const int n = blockIdx.x * 4 + w;
    const int c4 = lane * 4;

    ushort4 q4 = *(const ushort4*)&KVQn[(size_t)n * 768 + 512 + c4];
    const float q0 = b2f(q4.x), q1 = b2f(q4.y), q2 = b2f(q4.z), q3 = b2f(q4.w);

    int rows[DV];
#pragma unroll
    for (int d = 0; d < DV; d++) rows[d] = n2e[(size_t)n * DV + d];

    ushort4 k4[DV], v4[DV];
#pragma unroll
    for (int d = 0; d < DV; d++) {
        const u16* base = KVe + (size_t)rows[d] * 512 + c4;
        k4[d] = *(const ushort4*)base;
        v4[d] = *(const ushort4*)(base + 256);
    }
    float p[DV];
#pragma unroll
    for (int d = 0; d < DV; d++)
        p[d] = q0 * b2f(k4[d].x) + q1 * b2f(k4[d].y)
             + q2 * b2f(k4[d].z) + q3 * b2f(k4[d].w);
#pragma unroll
    for (int off = 32; off; off >>= 1)
#pragma unroll
        for (int d = 0; d < DV; d++) p[d] += __shfl_xor(p[d], off, 64);

#pragma unroll
    for (int d = 0; d < DV; d++)
        p[d] = (p[d] > 0.f ? p[d] : 0.01f * p[d]) * ATT_SCALE
             + cent2[(size_t)n * DV + d];
    float mx = p[0];
#pragma unroll
    for (int d = 1; d < DV; d++) mx = fmaxf(mx, p[d]);
    float s = 0.f;
#pragma unroll
    for (int d = 0; d < DV; d++) { p[d] = __expf(p[d] - mx); s += p[d]; }
    const float inv = 1.f / s;

    float a0 = 0.f, a1 = 0.f, a2 = 0.f, a3 = 0.f;
#pragma unroll
    for (int d = 0; d < DV; d++) {
        float sd = p[d] * inv;
        a0 = fmaf(sd, b2f(v4[d].x), a0); a1 = fmaf(sd, b2f(v4[d].y), a1);
        a2 = fmaf(sd, b2f(v4[d].z), a2); a3 = fmaf(sd, b2f(v4[d].w), a3);
    }
    ushort4 f4 = *(const ushort4*)&FV[(size_t)n * DIM + c4];
    float x0 = a0 + b2f(f4.x), x1 = a1 + b2f(f4.y);
    float x2 = a2 + b2f(f4.z), x3 = a3 + b2f(f4.w);

    float mu = x0 + x1 + x2 + x3;
#pragma unroll
    for (int off = 32; off; off >>= 1) mu += __shfl_xor(mu, off, 64);
    mu *= (1.f / DIM);
    float d0 = x0 - mu, d1 = x1 - mu, d2 = x2 - mu, d3 = x3 - mu;
    float var = d0 * d0 + d1 * d1 + d2 * d2 + d3 * d3;
#pragma unroll
    for (int off = 32; off; off >>= 1) var += __shfl_xor(var, off, 64);
    var *= (1.f / DIM);
    float r = rsqrtf(var + LN_EPS);
    float4 gv = *(const float4*)&g[c4];
    float4 bv = *(const float4*)&bb[c4];
    ushort4 o;
    o.x = f2b(d0 * r * gv.x + bv.x); o.y = f2b(d1 * r * gv.y + bv.y);
    o.z = f2b(d2 * r * gv.z + bv.z); o.w = f2b(d3 * r * gv.w + bv.w);
    *(ushort4*)&XV[(size_t)n * DIM + c4] = o;
}

extern "C" void kernel_launch(void* const* d_in, const int* in_sizes, int n_in,
                              void* d_out, int out_size, void* d_ws, size_t ws_size,
                              hipStream_t stream)
{
    const float* vfeat  = (const float*)d_in[0];
    const float* efeat  = (const float*)d_in[1];
    const float* eign   = (const float*)d_in[2];
    const float* gcn    = (const float*)d_in[3];
    const float* cent1  = (const float*)d_in[4];
    const float* cent2  = (const float*)d_in[5];
    const int*   cidx   = (const int*)d_in[6];
    const int*   uidx   = (const int*)d_in[7];
    const int*   e2n    = (const int*)d_in[8];
    const int*   n2e    = (const int*)d_in[9];
    const float* W_vtx  = (const float*)d_in[10]; const float* b_vtx = (const float*)d_in[11];
    const float* W_pe   = (const float*)d_in[12]; const float* b_pe  = (const float*)d_in[13];
    const float* cs_emb = (const float*)d_in[14]; const float* un_emb= (const float*)d_in[15];
    const float* W_kv   = (const float*)d_in[16]; const float* b_kv  = (const float*)d_in[17];
    const float* W_vv   = (const float*)d_in[18]; const float* b_vv  = (const float*)d_in[19];
    const float* W_qe   = (const float*)d_in[20]; const float* b_qe  = (const float*)d_in[21];
    const float* W_ke   = (const float*)d_in[22]; const float* b_ke  = (const float*)d_in[23];
    const float* W_ve   = (const float*)d_in[24]; const float* b_ve  = (const float*)d_in[25];
    const float* W_qv   = (const float*)d_in[26]; const float* b_qv  = (const float*)d_in[27];
    const float* W_l1   = (const float*)d_in[28]; const float* b_l1  = (const float*)d_in[29];
    const float* W_l2   = (const float*)d_in[30]; const float* b_l2  = (const float*)d_in[31];
    const float* W_l3   = (const float*)d_in[32]; const float* b_l3  = (const float*)d_in[33];
    const float* W_l4   = (const float*)d_in[34]; const float* b_l4  = (const float*)d_in[35];
    const float* ln1_g  = (const float*)d_in[36]; const float* ln1_b = (const float*)d_in[37];
    const float* ln2_g  = (const float*)d_in[38]; const float* ln2_b = (const float*)d_in[39];
    const float* W_cls  = (const float*)d_in[40]; const float* b_cls = (const float*)d_in[41];
    float* out = (float*)d_out;

    const size_t NE = (size_t)N_NODES * DIM;   // 10,240,000
    const size_t EE = (size_t)N_EDGES * DIM;   //  2,048,000
    u16* ws = (u16*)d_ws;
    u16* FVb  = ws;                 // assembled feat_v; reused for final feat_v
    u16* Vb   = FVb + NE;           // bf16 vfeat; reused as T0 (l3 out)
    u16* Gb   = Vb + NE;            // bf16 eign
    u16* KVQn = Gb + NE / 4;        // [N][768] k_n|v_n|q_v
    u16* B2   = KVQn + 3 * NE;      // x_v
    u16* Eb   = B2 + NE;            // bf16 efeat; reused as TE (l1 out)
    u16* QEb  = Eb + EE;
    u16* XE   = QEb + EE;
    u16* FE   = XE + EE;            // feat_e (LN-fused)
    u16* KVe  = FE + EE;            // [E][512] k_e|v_e
    u16* Wp   = KVe + 2 * EE;       // 13 * 65536
    u16* Wt_vtx = Wp +  0 * 65536;
    u16* Wt_pe  = Wp +  1 * 65536;
    u16* Wt_kvq = Wp +  2 * 65536;  // slots 2,3,4 = [768][256]
    u16* Wt_qe  = Wp +  5 * 65536;
    u16* Wt_kve = Wp +  6 * 65536;  // slots 6,7 = [512][256]
    u16* Wt_l1  = Wp +  8 * 65536;
    u16* Wt_l2  = Wp +  9 * 65536;
    u16* Wt_l3  = Wp + 10 * 65536;
    u16* Wt_l4  = Wp + 11 * 65536;
    u16* Wt_cls = Wp + 12 * 65536;
    u16* T0 = Vb;                   // alias (Vb dead after assembly GEMM)
    u16* TE = Eb;                   // alias (Eb dead after q_e GEMM)

    const dim3 blk(256);
    const dim3 gW(8, 8, 13);
    const dim3 gA(2, N_NODES / 64);    // assembly, Nd=256
    const dim3 gKVQ(6, N_NODES / 64);  // Nd=768
    const dim3 gQE(2, N_EDGES / 64);
    const dim3 gL1(2, N_EDGES / 64);
    const dim3 gLN_E(1, N_EDGES / 64);
    const dim3 gKVe(4, N_EDGES / 64);
    const dim3 gL3(2, N_NODES / 64);
    const dim3 gLN_N(1, N_NODES / 64);
    const dim3 gCl(1, N_NODES / 64);

    // ---- prep ----
    prep_weights<<<gW, blk, 0, stream>>>(
        W_vtx, W_pe, W_kv, W_vv, W_qv, W_qe, W_ke, W_ve,
        W_l1, W_l2, W_l3, W_l4, W_cls, Wp);
    cast_all<<<2048, blk, 0, stream>>>(vfeat, eign, efeat, Vb, Gb, Eb);

    // ---- feature assembly (dual-source: vfeat K=256 then eign K=64) ----
    gemm_mfma<3, true><<<gA, blk, 0, stream>>>(Vb, Gb, Wt_vtx, Wt_pe,
        b_vtx, b_pe, nullptr, gcn, cs_emb, un_emb, cidx, uidx,
        FVb, N_NODES, 256, 320, DIM);

    // ---- stage 1 ----
    gemm_mfma<0, false><<<gKVQ, blk, 0, stream>>>(FVb, nullptr, Wt_kvq, nullptr,
        b_kv, b_vv, b_qv, nullptr, nullptr, nullptr, nullptr, nullptr,
        KVQn, N_NODES, 256, 256, 768);                                   // k|v|q
    gemm_mfma<0, false><<<gQE, blk, 0, stream>>>(Eb, nullptr, Wt_qe, nullptr,
        b_qe, nullptr, nullptr, nullptr, nullptr, nullptr, nullptr, nullptr,
        QEb, N_EDGES, 256, 256, QDIM);                                   // q_e
    edge_attn<<<N_EDGES / 4, blk, 0, stream>>>(KVQn, QEb, efeat, e2n, cent1,
        ln1_g, ln1_b, XE);
    gemm_mfma<1, false><<<gL1, blk, 0, stream>>>(XE, nullptr, Wt_l1, nullptr,
        b_l1, nullptr, nullptr, nullptr, nullptr, nullptr, nullptr, nullptr,
        TE, N_EDGES, 256, 256, QDIM);                                    // relu(l1)
    gemm_ln<<<gLN_E, blk, 0, stream>>>(TE, Wt_l2, b_l2, XE, ln1_g, ln1_b,
        FE, N_EDGES);                                                    // feat_e

    // ---- stage 2 ----
    gemm_mfma<0, false><<<gKVe, blk, 0, stream>>>(FE, nullptr, Wt_kve, nullptr,
        b_ke, b_ve, nullptr, nullptr, nullptr, nullptr, nullptr, nullptr,
        KVe, N_EDGES, 256, 256, 512);                                    // k_e|v_e
    node_attn<<<N_NODES / 4, blk, 0, stream>>>(KVe, KVQn, FVb, n2e, cent2,
        ln2_g, ln2_b, B2);                                               // x_v
    gemm_mfma<1, false><<<gL3, blk, 0, stream>>>(B2, nullptr, Wt_l3, nullptr,
        b_l3, nullptr, nullptr, nullptr, nullptr, nullptr, nullptr, nullptr,
        T0, N_NODES, 256, 256, QDIM);                                    // relu(l3)
    gemm_ln<<<gLN_N, blk, 0, stream>>>(T0, Wt_l4, b_l4, B2, ln2_g, ln2_b,
        FVb, N_NODES);                                                   // feat_v

    // ---- classifier ----
    gemm_mfma<4, false><<<gCl, blk, 0, stream>>>(FVb, nullptr, Wt_cls, nullptr,
        b_cls, nullptr, nullptr, nullptr, nullptr, nullptr, nullptr, nullptr,
        out, N_NODES, 256, 256, NCLS);
}